// Round 13
// baseline (457.935 us; speedup 1.0000x reference)
//
#include <hip/hip_runtime.h>

// 4D conv net, MI355X. S=30, B=2, ch 1->10->10->1, kernel 3^4, pad 1, ReLU.
// out = net(x,w) + net(x,w_swap), w_swap has (k1,k2)<->(k3,k4).
// R7: all layers as 32x32x16 bf16 MFMA; epilogue k4-combine via per-wave LDS.
// R8: XCD-chunk swizzle, full-line stores, barrier-free epilogue.
// R13: layer-0 K-packed conv0_k (9 taps -> 1, 12 MFMAs).
// R17 (best, 69.2 us/conv_k): B-table in LDS, rotate-A depth-1 prefetch.
// R14-R16,R18,R19: pipeline/occupancy/traffic variants all regressed ->
// R17 geometry = latency/locality equilibrium (R19: +occupancy grew the
// XCD window past 4MB L2, FETCH 35->58MB).
// R20: keep R17 kernels; attack the ~110us outside conv_k:
//  (a) s_setprio(1) around MFMA clusters (barrier-free loop -> waves at
//      different phases, the regime where setprio measured +4-7%);
//  (b) fuse fragprep+zerok into one prep dispatch;
//  (c) fuse the independent pair {L2 branch0, L0 branch1} into one z=8
//      dispatch (no shared tensors, no race) -> 9 dispatches -> 6, conv0
//      hides in conv2's tail.

static constexpr int S  = 30;
static constexpr long S4 = 810000;
static constexpr size_t PLANE = 32768;                  // 32*32*16*2 B
static constexpr size_t YBYTES = (size_t)1800 * PLANE;  // [b(2)][g1][g2]

typedef __bf16 bf16x8 __attribute__((ext_vector_type(8)));
typedef float  f32x16 __attribute__((ext_vector_type(16)));
typedef unsigned int  u32;
typedef unsigned short u16;

static __device__ __forceinline__ u16 f2bf(float f) {
    u32 u = __builtin_bit_cast(u32, f);
    return (u16)((u + 0x7fffu + ((u >> 16) & 1u)) >> 16);
}

// ---------------------------------------------------------------------------
// Fused prep: blocks 0..41 build the B-fragment tables; blocks 42..1841 zero
// the halo positions of all 1800 planes of y1 and y2.
// Main table: [set(6)][k12(9)][k3(3)][lane(64)] uint4 (sets 0/1 unused).
// L0-packed (appended): [branch(2)][k3(3)][lane(64)] uint4,
//   B[k=k12][n=k4*10+co] = w1[co, perm(k1,k2,k3,k4)], k12 = hl*8+j (<9).
__global__ __launch_bounds__(256) void prep_k(u32* __restrict__ ft,
    const float* __restrict__ w1, const float* __restrict__ w2,
    const float* __restrict__ w3, u16* __restrict__ y1, u16* __restrict__ y2)
{
    const int tid = threadIdx.x;
    if (blockIdx.x >= 42) {                    // ---- zerok role ----
        const int pb = blockIdx.x - 42;
        if (tid >= 124) return;
        int hp, tp;
        if (tid < 32)      { hp = 0;        tp = tid; }
        else if (tid < 64) { hp = 31;       tp = tid - 32; }
        else if (tid < 94) { hp = tid - 63; tp = 0; }
        else               { hp = tid - 93; tp = 31; }
        const size_t off = (size_t)pb * PLANE + hp * 1024 + tp * 32;
        const uint4 z = make_uint4(0, 0, 0, 0);
        *(uint4*)((char*)y1 + off)      = z;
        *(uint4*)((char*)y1 + off + 16) = z;
        *(uint4*)((char*)y2 + off)      = z;
        *(uint4*)((char*)y2 + off + 16) = z;
        return;
    }
    // ---- fragprep role ----
    const int gid = blockIdx.x * 256 + tid;    // 0..10751
    const int lane = gid & 63;
    const int n = lane & 31, hl = lane >> 5;
    u16 us[8];
#pragma unroll
    for (int j = 0; j < 8; ++j) us[j] = 0;

    if (gid < 6 * 27 * 64) {
        int r = gid >> 6;
        const int k3 = r % 3; r /= 3;
        const int k12 = r % 9; const int set = r / 9;
        const int layer = set >> 1, swap = set & 1;
        const int k1 = k12 / 3, k2 = k12 % 3;
        if (n < 30) {
            const int k4 = (n < 10) ? 0 : ((n < 20) ? 1 : 2);
            const int co = n - 10 * k4;
            const int i1 = swap ? k3 : k1, i2 = swap ? k4 : k2;
            const int i3 = swap ? k1 : k3, i4 = swap ? k2 : k4;
            const int widx = ((i1 * 3 + i2) * 3 + i3) * 3 + i4;
#pragma unroll
            for (int j = 0; j < 8; ++j) {
                const int k = hl * 8 + j;
                float wv = 0.f;
                if (layer == 0) { if (k == 0) wv = w1[co * 81 + widx]; }
                else if (layer == 1) { if (k < 10) wv = w2[(co * 10 + k) * 81 + widx]; }
                else { if (k < 10 && co == 0) wv = w3[k * 81 + widx]; }
                us[j] = f2bf(wv);
            }
        }
    } else {
        const int idx = gid - 6 * 27 * 64;       // 0..383
        int r = idx >> 6;                        // 0..5
        const int k3 = r % 3, swap = r / 3;
        if (n < 30) {
            const int k4 = (n < 10) ? 0 : ((n < 20) ? 1 : 2);
            const int co = n - 10 * k4;
#pragma unroll
            for (int j = 0; j < 8; ++j) {
                const int k12 = hl * 8 + j;
                if (k12 < 9) {
                    const int k1 = k12 / 3, k2 = k12 % 3;
                    const int i1 = swap ? k3 : k1, i2 = swap ? k4 : k2;
                    const int i3 = swap ? k1 : k3, i4 = swap ? k2 : k4;
                    const int widx = ((i1 * 3 + i2) * 3 + i3) * 3 + i4;
                    us[j] = f2bf(w1[co * 81 + widx]);
                }
            }
        }
    }
    u32* o = ft + (size_t)gid * 4;
    o[0] = (u32)us[0] | ((u32)us[1] << 16);
    o[1] = (u32)us[2] | ((u32)us[3] << 16);
    o[2] = (u32)us[4] | ((u32)us[5] << 16);
    o[3] = (u32)us[6] | ((u32)us[7] << 16);
}

// ---------------------------------------------------------------------------
// Layer-0 body (K-packed, one tap, 12 MFMAs) as a device function so it can
// run standalone (branch 0) or fused (branch 1 inside conv20_k).
static __device__ __forceinline__ void conv0_body(
    float (*E)[1056], const float* __restrict__ x, const uint4* __restrict__ bt,
    const float* __restrict__ bias, void* __restrict__ outp, int zq)
{
    const int wgid = blockIdx.x + S * blockIdx.y + 900 * zq;
    const int id2  = (wgid & 7) * 450 + (wgid >> 3);
    const int half = id2 & 1;
    int sp = id2 >> 1;
    const int w1i = sp % S; sp /= S;
    const int h1  = sp % S;
    const int b   = sp / S;

    const int tid = threadIdx.x;
    const int lane = tid & 63, wv = tid >> 6;
    const int m = lane & 31, hl = lane >> 5;
    const int rbase = half * 15 + wv * 4;

    uint4 Bs[3];
#pragma unroll
    for (int ss = 0; ss < 3; ++ss) Bs[ss] = bt[ss * 64 + lane];

    int gof[9]; int gokm = 0;
#pragma unroll
    for (int k12 = 0; k12 < 9; ++k12) {
        const int g1 = h1 + k12 / 3 - 1, g2 = w1i + k12 % 3 - 1;
        gof[k12] = 0;
        if (g1 >= 0 && g1 < S && g2 >= 0 && g2 < S) {
            gof[k12] = (g1 * S + g2) * 900; gokm |= 1 << k12;
        }
    }
    const float* xb = x + (size_t)b * S4;

    uint4 F[6];
#pragma unroll
    for (int f = 0; f < 6; ++f) {
        const int hp = rbase + f;
        const bool rk = (hp >= 1 && hp <= 30 && m >= 1 && m <= 30);
        const int ro = (hp - 1) * 30 + (m - 1);
        u16 av[8];
#pragma unroll
        for (int j = 0; j < 8; ++j) av[j] = 0;
        if (hl == 0) {
#pragma unroll
            for (int j = 0; j < 8; ++j) {
                float v = 0.f;
                if (rk && ((gokm >> j) & 1)) v = xb[gof[j] + ro];
                av[j] = f2bf(v);
            }
        } else {
            float v = 0.f;
            if (rk && ((gokm >> 8) & 1)) v = xb[gof[8] + ro];
            av[0] = f2bf(v);
        }
        F[f] = make_uint4((u32)av[0] | ((u32)av[1] << 16),
                          (u32)av[2] | ((u32)av[3] << 16),
                          (u32)av[4] | ((u32)av[5] << 16),
                          (u32)av[6] | ((u32)av[7] << 16));
    }

    f32x16 acc[4];
#pragma unroll
    for (int r = 0; r < 4; ++r)
#pragma unroll
        for (int e = 0; e < 16; ++e) acc[r][e] = 0.f;
    __builtin_amdgcn_s_setprio(1);
#pragma unroll
    for (int ss = 0; ss < 3; ++ss)
#pragma unroll
        for (int r = 0; r < 4; ++r)
            acc[r] = __builtin_amdgcn_mfma_f32_32x32x16_bf16(
                __builtin_bit_cast(bf16x8, F[r + ss]),
                __builtin_bit_cast(bf16x8, Bs[ss]), acc[r], 0, 0, 0);
    __builtin_amdgcn_s_setprio(0);

    float* Ew = E[wv];
    for (int r = 0; r < 4; ++r) {
        if (wv == 3 && r == 3) continue;
#pragma unroll
        for (int gq = 0; gq < 4; ++gq)
#pragma unroll
            for (int r4 = 0; r4 < 4; ++r4)
                Ew[m * 33 + 4 * hl + 8 * gq + r4] = acc[r][gq * 4 + r4];

        const int h2 = rbase + r;
        char* pl = (char*)outp + ((size_t)b * 900 + h1 * S + w1i) * PLANE
                   + (size_t)(h2 + 1) * 1024;
        const int t = lane >> 1, h8 = lane & 1;
        if (t < 30) {
            u32 wo[4];
#pragma unroll
            for (int p = 0; p < 4; ++p) {
                const int c0 = 8 * h8 + 2 * p, c1 = c0 + 1;
                float v0 = 0.f, v1 = 0.f;
                if (c0 < 10)
                    v0 = fmaxf(Ew[c0 * 33 + t] + Ew[(10 + c0) * 33 + t + 1]
                             + Ew[(20 + c0) * 33 + t + 2] + bias[c0], 0.f);
                if (c1 < 10)
                    v1 = fmaxf(Ew[c1 * 33 + t] + Ew[(10 + c1) * 33 + t + 1]
                             + Ew[(20 + c1) * 33 + t + 2] + bias[c1], 0.f);
                wo[p] = (u32)f2bf(v0) | ((u32)f2bf(v1) << 16);
            }
            *(uint4*)(pl + (t + 1) * 32 + h8 * 16) =
                make_uint4(wo[0], wo[1], wo[2], wo[3]);
        }
    }
}

__global__ __launch_bounds__(256, 4) void conv0_k(
    const float* __restrict__ x, const uint4* __restrict__ bt,
    const float* __restrict__ bias, void* __restrict__ outp)
{
    __shared__ float E[4][1056];
    conv0_body(E, x, bt, bias, outp, blockIdx.z);
}

// ---------------------------------------------------------------------------
// Layers 1/2 body (R17, exact): B-table staged to LDS, rotate-A depth-1
// prefetch, barrier-free per-wave epilogue. setprio around MFMA clusters.
template<int LAYER, bool ACCUM>
static __device__ __forceinline__ void conv_body(
    float (*E)[1056], uint4* BT,
    const void* __restrict__ inp, const u32* __restrict__ ftab,
    const float* __restrict__ bias, void* __restrict__ outp, int zq)
{
    const int tid = threadIdx.x;
    {
        const uint4* g = (const uint4*)ftab;
#pragma unroll
        for (int j = 0; j < 7; ++j) {
            const int idx = j * 256 + tid;
            if (idx < 1728) BT[idx] = g[idx];
        }
    }
    __syncthreads();

    const int wgid = blockIdx.x + S * blockIdx.y + 900 * zq;
    const int id2  = (wgid & 7) * 450 + (wgid >> 3);
    const int half = id2 & 1;
    int sp = id2 >> 1;
    const int w1i = sp % S; sp /= S;
    const int h1  = sp % S;
    const int b   = sp / S;

    const int lane = tid & 63, wv = tid >> 6;
    const int m = lane & 31, hl = lane >> 5;
    const int rbase = half * 15 + wv * 4;

    int rofs[6];
#pragma unroll
    for (int f = 0; f < 6; ++f) {
        int rr = rbase + f; if (rr > 31) rr = 31;
        rofs[f] = rr * 1024;
    }

    int kl[9], nk = 0;
#pragma unroll
    for (int k12 = 0; k12 < 9; ++k12) {
        const int g1 = h1 + k12 / 3 - 1, g2 = w1i + k12 % 3 - 1;
        if (g1 >= 0 && g1 < S && g2 >= 0 && g2 < S)
            kl[nk++] = (g1 * S + g2) | (k12 << 10);
    }

    f32x16 acc[4];
#pragma unroll
    for (int r = 0; r < 4; ++r)
#pragma unroll
        for (int e = 0; e < 16; ++e) acc[r][e] = 0.f;

    auto loadA = [&](uint4* Fd, int g) {
        const char* P = (const char*)inp + ((size_t)b * 900 + g) * PLANE
                        + m * 32 + hl * 16;
#pragma unroll
        for (int f = 0; f < 6; ++f)
            Fd[f] = *(const uint4*)(P + rofs[f]);
    };

    uint4 B0[3];
    {
        const int k0 = kl[0] >> 10;
#pragma unroll
        for (int f = 0; f < 3; ++f) B0[f] = BT[(k0 * 3 + f) * 64 + lane];
    }
    uint4 F[6];
    loadA(F, kl[0] & 1023);

    for (int ki = 0; ki + 1 < nk; ++ki) {
        const int gn = kl[ki + 1] & 1023, kn = kl[ki + 1] >> 10;
        uint4 FN[6];
        loadA(FN, gn);
        uint4 BN[3];
#pragma unroll
        for (int f = 0; f < 3; ++f) BN[f] = BT[(kn * 3 + f) * 64 + lane];

        __builtin_amdgcn_s_setprio(1);
#pragma unroll
        for (int ss = 0; ss < 3; ++ss)
#pragma unroll
            for (int r = 0; r < 4; ++r)
                acc[r] = __builtin_amdgcn_mfma_f32_32x32x16_bf16(
                    __builtin_bit_cast(bf16x8, F[r + ss]),
                    __builtin_bit_cast(bf16x8, B0[ss]), acc[r], 0, 0, 0);
        __builtin_amdgcn_s_setprio(0);

#pragma unroll
        for (int f = 0; f < 6; ++f) F[f] = FN[f];
#pragma unroll
        for (int f = 0; f < 3; ++f) B0[f] = BN[f];
    }
    __builtin_amdgcn_s_setprio(1);
#pragma unroll
    for (int ss = 0; ss < 3; ++ss)
#pragma unroll
        for (int r = 0; r < 4; ++r)
            acc[r] = __builtin_amdgcn_mfma_f32_32x32x16_bf16(
                __builtin_bit_cast(bf16x8, F[r + ss]),
                __builtin_bit_cast(bf16x8, B0[ss]), acc[r], 0, 0, 0);
    __builtin_amdgcn_s_setprio(0);

    float* Ew = E[wv];
    for (int r = 0; r < 4; ++r) {
        if (wv == 3 && r == 3) continue;
#pragma unroll
        for (int gq = 0; gq < 4; ++gq)
#pragma unroll
            for (int r4 = 0; r4 < 4; ++r4)
                Ew[m * 33 + 4 * hl + 8 * gq + r4] = acc[r][gq * 4 + r4];

        const int h2 = rbase + r;
        if (LAYER <= 1) {
            char* pl = (char*)outp + ((size_t)b * 900 + h1 * S + w1i) * PLANE
                       + (size_t)(h2 + 1) * 1024;
            const int t = lane >> 1, h8 = lane & 1;
            if (t < 30) {
                u32 wo[4];
#pragma unroll
                for (int p = 0; p < 4; ++p) {
                    const int c0 = 8 * h8 + 2 * p, c1 = c0 + 1;
                    float v0 = 0.f, v1 = 0.f;
                    if (c0 < 10)
                        v0 = fmaxf(Ew[c0 * 33 + t] + Ew[(10 + c0) * 33 + t + 1]
                                 + Ew[(20 + c0) * 33 + t + 2] + bias[c0], 0.f);
                    if (c1 < 10)
                        v1 = fmaxf(Ew[c1 * 33 + t] + Ew[(10 + c1) * 33 + t + 1]
                                 + Ew[(20 + c1) * 33 + t + 2] + bias[c1], 0.f);
                    wo[p] = (u32)f2bf(v0) | ((u32)f2bf(v1) << 16);
                }
                *(uint4*)(pl + (t + 1) * 32 + h8 * 16) =
                    make_uint4(wo[0], wo[1], wo[2], wo[3]);
            }
        } else {
            if (lane < 30) {
                const int t = lane;
                float v = Ew[t] + Ew[330 + t + 1] + Ew[660 + t + 2] + bias[0];
                v = fmaxf(v, 0.f);
                float* o = (float*)outp + (size_t)b * S4
                           + (size_t)(h1 * S + w1i) * 900 + h2 * 30 + t;
                if (ACCUM) *o += v; else *o = v;
            }
        }
    }
}

template<int LAYER, bool ACCUM>
__global__ __launch_bounds__(256, 2) void conv_k(
    const void* __restrict__ inp, const u32* __restrict__ ftab,
    const float* __restrict__ bias, void* __restrict__ outp)
{
    __shared__ float E[4][1056];
    __shared__ uint4 BT[1728];
    conv_body<LAYER, ACCUM>(E, BT, inp, ftab, bias, outp, blockIdx.z);
}

// ---------------------------------------------------------------------------
// Fused dispatch: z 0..3 = layer-2 branch0 (y2 -> out, write);
//                 z 4..7 = layer-0 branch1 (x -> y1). Independent tensors.
__global__ __launch_bounds__(256, 2) void conv20_k(
    const void* __restrict__ y2, const u32* __restrict__ ft2,
    const float* __restrict__ b3, float* __restrict__ out,
    const float* __restrict__ x, const uint4* __restrict__ bt0,
    const float* __restrict__ b1, void* __restrict__ y1)
{
    __shared__ float E[4][1056];
    __shared__ uint4 BT[1728];
    const int bz = blockIdx.z;
    if (bz < 4)
        conv_body<2, false>(E, BT, y2, ft2, b3, (void*)out, bz);
    else
        conv0_body(E, x, bt0, b1, y1, bz - 4);
}

// ---------------------------------------------------------------------------
extern "C" void kernel_launch(void* const* d_in, const int* in_sizes, int n_in,
                              void* d_out, int out_size, void* d_ws, size_t ws_size,
                              hipStream_t stream)
{
    const float* x   = (const float*)d_in[0];
    const float* w1p = (const float*)d_in[1];
    const float* b1p = (const float*)d_in[2];
    const float* w2p = (const float*)d_in[3];
    const float* b2p = (const float*)d_in[4];
    const float* w3p = (const float*)d_in[5];
    const float* b3p = (const float*)d_in[6];
    float* out = (float*)d_out;

    // ws: fragtab (6*27*64 + 2*3*64) uint4 = 172032 B | y1 59 MB | y2 59 MB
    u32* ft = (u32*)d_ws;
    const uint4* ftL0 = (const uint4*)d_ws + 6 * 27 * 64;
    u16* y1 = (u16*)((char*)d_ws + 172032);
    u16* y2 = (u16*)((char*)y1 + YBYTES);

    prep_k<<<1842, 256, 0, stream>>>(ft, w1p, w2p, w3p, y1, y2);

    const u32* f2b0 = ft + (size_t)2 * 27 * 64 * 4;
    const u32* f2b1 = ft + (size_t)3 * 27 * 64 * 4;
    const u32* f3b0 = ft + (size_t)4 * 27 * 64 * 4;
    const u32* f3b1 = ft + (size_t)5 * 27 * 64 * 4;

    dim3 g4(S, S, 4), g8(S, S, 8), blk(256);
    // branch 0: L0, L1
    conv0_k<<<g4, blk, 0, stream>>>(x, ftL0 + 0 * 192, b1p, (void*)y1);
    conv_k<1, false><<<g4, blk, 0, stream>>>(y1, f2b0, b2p, (void*)y2);
    // fused: L2 branch0 (y2 -> out) + L0 branch1 (x -> y1)
    conv20_k<<<g8, blk, 0, stream>>>(y2, f3b0, b3p, out,
                                     x, ftL0 + 1 * 192, b1p, (void*)y1);
    // branch 1: L1, L2(accum)
    conv_k<1, false><<<g4, blk, 0, stream>>>(y1, f2b1, b2p, (void*)y2);
    conv_k<2, true><<<g4, blk, 0, stream>>>(y2, f3b1, b3p, (void*)out);
}

// Round 15
// 384.058 us; speedup vs baseline: 1.1924x; 1.1924x over previous
//
#include <hip/hip_runtime.h>

// 4D conv net, MI355X. S=30, B=2, ch 1->10->10->1, kernel 3^4, pad 1, ReLU.
// out = net(x,w) + net(x,w_swap), w_swap has (k1,k2)<->(k3,k4).
// R7: all layers as 32x32x16 bf16 MFMA; epilogue k4-combine via per-wave LDS.
// R8: XCD-chunk swizzle, full-line stores, barrier-free epilogue.
// R13: layer-0 K-packed conv0_k (9 taps -> 1, 12 MFMAs).
// R17 (champion, 69.2 us/conv_k, 387 total): B-table in LDS, rotate-A
// depth-1 prefetch, launch_bounds(256,2).
// R9/R11/R14/R15/R16/R18/R19/R20: eight structural variants (pipelining,
// occupancy, traffic, fusion, setprio) all regressed -> R17 is a
// latency/locality equilibrium; perturbations of regs/occupancy/fusion
// all disturb it.
// R21: clean revert to R17 kernels (byte-identical conv0_k/conv_k) +
// the one zero-risk R20 piece: fragprep+zerok merged into one prep
// dispatch (independent work, removes a dispatch boundary).
// R22: resubmission of R21 — round-14 failure was container acquisition
// (infra), not kernel; source unchanged.

static constexpr int S  = 30;
static constexpr long S4 = 810000;
static constexpr size_t PLANE = 32768;                  // 32*32*16*2 B
static constexpr size_t YBYTES = (size_t)1800 * PLANE;  // [b(2)][g1][g2]

typedef __bf16 bf16x8 __attribute__((ext_vector_type(8)));
typedef float  f32x16 __attribute__((ext_vector_type(16)));
typedef unsigned int  u32;
typedef unsigned short u16;

static __device__ __forceinline__ u16 f2bf(float f) {
    u32 u = __builtin_bit_cast(u32, f);
    return (u16)((u + 0x7fffu + ((u >> 16) & 1u)) >> 16);
}

// ---------------------------------------------------------------------------
// Fused prep: blocks 0..41 build the B-fragment tables (42*256 = 10752 ids
// exactly); blocks 42..1841 zero the halo positions of y1/y2 planes.
// Main table: [set(6)][k12(9)][k3(3)][lane(64)] uint4 (sets 0/1 unused).
// L0-packed (appended): [branch(2)][k3(3)][lane(64)] uint4,
//   B[k=k12][n=k4*10+co] = w1[co, perm(k1,k2,k3,k4)], k12 = hl*8+j (<9).
__global__ __launch_bounds__(256) void prep_k(u32* __restrict__ ft,
    const float* __restrict__ w1, const float* __restrict__ w2,
    const float* __restrict__ w3, u16* __restrict__ y1, u16* __restrict__ y2)
{
    const int tid = threadIdx.x;
    if (blockIdx.x >= 42) {                    // ---- zerok role ----
        const int pb = blockIdx.x - 42;
        if (tid >= 124) return;
        int hp, tp;
        if (tid < 32)      { hp = 0;        tp = tid; }
        else if (tid < 64) { hp = 31;       tp = tid - 32; }
        else if (tid < 94) { hp = tid - 63; tp = 0; }
        else               { hp = tid - 93; tp = 31; }
        const size_t off = (size_t)pb * PLANE + hp * 1024 + tp * 32;
        const uint4 z = make_uint4(0, 0, 0, 0);
        *(uint4*)((char*)y1 + off)      = z;
        *(uint4*)((char*)y1 + off + 16) = z;
        *(uint4*)((char*)y2 + off)      = z;
        *(uint4*)((char*)y2 + off + 16) = z;
        return;
    }
    // ---- fragprep role ----
    const int gid = blockIdx.x * 256 + tid;    // 0..10751
    const int lane = gid & 63;
    const int n = lane & 31, hl = lane >> 5;
    u16 us[8];
#pragma unroll
    for (int j = 0; j < 8; ++j) us[j] = 0;

    if (gid < 6 * 27 * 64) {
        int r = gid >> 6;
        const int k3 = r % 3; r /= 3;
        const int k12 = r % 9; const int set = r / 9;
        const int layer = set >> 1, swap = set & 1;
        const int k1 = k12 / 3, k2 = k12 % 3;
        if (n < 30) {
            const int k4 = (n < 10) ? 0 : ((n < 20) ? 1 : 2);
            const int co = n - 10 * k4;
            const int i1 = swap ? k3 : k1, i2 = swap ? k4 : k2;
            const int i3 = swap ? k1 : k3, i4 = swap ? k2 : k4;
            const int widx = ((i1 * 3 + i2) * 3 + i3) * 3 + i4;
#pragma unroll
            for (int j = 0; j < 8; ++j) {
                const int k = hl * 8 + j;
                float wv = 0.f;
                if (layer == 0) { if (k == 0) wv = w1[co * 81 + widx]; }
                else if (layer == 1) { if (k < 10) wv = w2[(co * 10 + k) * 81 + widx]; }
                else { if (k < 10 && co == 0) wv = w3[k * 81 + widx]; }
                us[j] = f2bf(wv);
            }
        }
    } else {
        const int idx = gid - 6 * 27 * 64;       // 0..383
        int r = idx >> 6;                        // 0..5
        const int k3 = r % 3, swap = r / 3;
        if (n < 30) {
            const int k4 = (n < 10) ? 0 : ((n < 20) ? 1 : 2);
            const int co = n - 10 * k4;
#pragma unroll
            for (int j = 0; j < 8; ++j) {
                const int k12 = hl * 8 + j;
                if (k12 < 9) {
                    const int k1 = k12 / 3, k2 = k12 % 3;
                    const int i1 = swap ? k3 : k1, i2 = swap ? k4 : k2;
                    const int i3 = swap ? k1 : k3, i4 = swap ? k2 : k4;
                    const int widx = ((i1 * 3 + i2) * 3 + i3) * 3 + i4;
                    us[j] = f2bf(w1[co * 81 + widx]);
                }
            }
        }
    }
    u32* o = ft + (size_t)gid * 4;
    o[0] = (u32)us[0] | ((u32)us[1] << 16);
    o[1] = (u32)us[2] | ((u32)us[3] << 16);
    o[2] = (u32)us[4] | ((u32)us[5] << 16);
    o[3] = (u32)us[6] | ((u32)us[7] << 16);
}

// ---------------------------------------------------------------------------
// Layer 0, K-packed: one "tap", 12 MFMAs per wave (R13, byte-identical).
__global__ __launch_bounds__(256, 4) void conv0_k(
    const float* __restrict__ x, const uint4* __restrict__ bt,
    const float* __restrict__ bias, void* __restrict__ outp)
{
    __shared__ float E[4][1056];
    const int wgid = blockIdx.x + S * blockIdx.y + 900 * blockIdx.z;
    const int id2  = (wgid & 7) * 450 + (wgid >> 3);
    const int half = id2 & 1;
    int sp = id2 >> 1;
    const int w1i = sp % S; sp /= S;
    const int h1  = sp % S;
    const int b   = sp / S;

    const int tid = threadIdx.x;
    const int lane = tid & 63, wv = tid >> 6;
    const int m = lane & 31, hl = lane >> 5;
    const int rbase = half * 15 + wv * 4;

    uint4 Bs[3];
#pragma unroll
    for (int ss = 0; ss < 3; ++ss) Bs[ss] = bt[ss * 64 + lane];

    int gof[9]; int gokm = 0;
#pragma unroll
    for (int k12 = 0; k12 < 9; ++k12) {
        const int g1 = h1 + k12 / 3 - 1, g2 = w1i + k12 % 3 - 1;
        gof[k12] = 0;
        if (g1 >= 0 && g1 < S && g2 >= 0 && g2 < S) {
            gof[k12] = (g1 * S + g2) * 900; gokm |= 1 << k12;
        }
    }
    const float* xb = x + (size_t)b * S4;

    uint4 F[6];
#pragma unroll
    for (int f = 0; f < 6; ++f) {
        const int hp = rbase + f;
        const bool rk = (hp >= 1 && hp <= 30 && m >= 1 && m <= 30);
        const int ro = (hp - 1) * 30 + (m - 1);
        u16 av[8];
#pragma unroll
        for (int j = 0; j < 8; ++j) av[j] = 0;
        if (hl == 0) {
#pragma unroll
            for (int j = 0; j < 8; ++j) {
                float v = 0.f;
                if (rk && ((gokm >> j) & 1)) v = xb[gof[j] + ro];
                av[j] = f2bf(v);
            }
        } else {
            float v = 0.f;
            if (rk && ((gokm >> 8) & 1)) v = xb[gof[8] + ro];
            av[0] = f2bf(v);
        }
        F[f] = make_uint4((u32)av[0] | ((u32)av[1] << 16),
                          (u32)av[2] | ((u32)av[3] << 16),
                          (u32)av[4] | ((u32)av[5] << 16),
                          (u32)av[6] | ((u32)av[7] << 16));
    }

    f32x16 acc[4];
#pragma unroll
    for (int r = 0; r < 4; ++r)
#pragma unroll
        for (int e = 0; e < 16; ++e) acc[r][e] = 0.f;
#pragma unroll
    for (int ss = 0; ss < 3; ++ss)
#pragma unroll
        for (int r = 0; r < 4; ++r)
            acc[r] = __builtin_amdgcn_mfma_f32_32x32x16_bf16(
                __builtin_bit_cast(bf16x8, F[r + ss]),
                __builtin_bit_cast(bf16x8, Bs[ss]), acc[r], 0, 0, 0);

    float* Ew = E[wv];
    for (int r = 0; r < 4; ++r) {
        if (wv == 3 && r == 3) continue;
#pragma unroll
        for (int gq = 0; gq < 4; ++gq)
#pragma unroll
            for (int r4 = 0; r4 < 4; ++r4)
                Ew[m * 33 + 4 * hl + 8 * gq + r4] = acc[r][gq * 4 + r4];

        const int h2 = rbase + r;
        char* pl = (char*)outp + ((size_t)b * 900 + h1 * S + w1i) * PLANE
                   + (size_t)(h2 + 1) * 1024;
        const int t = lane >> 1, h8 = lane & 1;
        if (t < 30) {
            u32 wo[4];
#pragma unroll
            for (int p = 0; p < 4; ++p) {
                const int c0 = 8 * h8 + 2 * p, c1 = c0 + 1;
                float v0 = 0.f, v1 = 0.f;
                if (c0 < 10)
                    v0 = fmaxf(Ew[c0 * 33 + t] + Ew[(10 + c0) * 33 + t + 1]
                             + Ew[(20 + c0) * 33 + t + 2] + bias[c0], 0.f);
                if (c1 < 10)
                    v1 = fmaxf(Ew[c1 * 33 + t] + Ew[(10 + c1) * 33 + t + 1]
                             + Ew[(20 + c1) * 33 + t + 2] + bias[c1], 0.f);
                wo[p] = (u32)f2bf(v0) | ((u32)f2bf(v1) << 16);
            }
            *(uint4*)(pl + (t + 1) * 32 + h8 * 16) =
                make_uint4(wo[0], wo[1], wo[2], wo[3]);
        }
    }
}

// ---------------------------------------------------------------------------
// Layers 1/2 (R17, byte-identical): B-table staged to LDS, rotate-A depth-1
// prefetch, barrier-free per-wave epilogue, launch_bounds(256,2).
template<int LAYER, bool ACCUM>
__global__ __launch_bounds__(256, 2) void conv_k(
    const void* __restrict__ inp, const u32* __restrict__ ftab,
    const float* __restrict__ bias, void* __restrict__ outp)
{
    __shared__ float E[4][1056];          // per-wave epilogue scratch
    __shared__ uint4 BT[1728];            // [k12(9)][k3(3)][lane(64)]

    const int tid = threadIdx.x;
    // ---- stage B table to LDS (27.6 KB, once per block) ----
    {
        const uint4* g = (const uint4*)ftab;
#pragma unroll
        for (int j = 0; j < 7; ++j) {
            const int idx = j * 256 + tid;
            if (idx < 1728) BT[idx] = g[idx];
        }
    }
    __syncthreads();

    const int wgid = blockIdx.x + S * blockIdx.y + 900 * blockIdx.z;
    const int id2  = (wgid & 7) * 450 + (wgid >> 3);
    const int half = id2 & 1;
    int sp = id2 >> 1;
    const int w1i = sp % S; sp /= S;
    const int h1  = sp % S;
    const int b   = sp / S;

    const int lane = tid & 63, wv = tid >> 6;
    const int m = lane & 31, hl = lane >> 5;
    const int rbase = half * 15 + wv * 4;

    int rofs[6];
#pragma unroll
    for (int f = 0; f < 6; ++f) {
        int rr = rbase + f; if (rr > 31) rr = 31;
        rofs[f] = rr * 1024;
    }

    int kl[9], nk = 0;
#pragma unroll
    for (int k12 = 0; k12 < 9; ++k12) {
        const int g1 = h1 + k12 / 3 - 1, g2 = w1i + k12 % 3 - 1;
        if (g1 >= 0 && g1 < S && g2 >= 0 && g2 < S)
            kl[nk++] = (g1 * S + g2) | (k12 << 10);
    }

    f32x16 acc[4];
#pragma unroll
    for (int r = 0; r < 4; ++r)
#pragma unroll
        for (int e = 0; e < 16; ++e) acc[r][e] = 0.f;

    auto loadA = [&](uint4* Fd, int g) {
        const char* P = (const char*)inp + ((size_t)b * 900 + g) * PLANE
                        + m * 32 + hl * 16;
#pragma unroll
        for (int f = 0; f < 6; ++f)
            Fd[f] = *(const uint4*)(P + rofs[f]);
    };

    uint4 B0[3];
    {
        const int k0 = kl[0] >> 10;
#pragma unroll
        for (int f = 0; f < 3; ++f) B0[f] = BT[(k0 * 3 + f) * 64 + lane];
    }
    uint4 F[6];
    loadA(F, kl[0] & 1023);

    for (int ki = 0; ki + 1 < nk; ++ki) {
        const int gn = kl[ki + 1] & 1023, kn = kl[ki + 1] >> 10;
        uint4 FN[6];
        loadA(FN, gn);
        uint4 BN[3];
#pragma unroll
        for (int f = 0; f < 3; ++f) BN[f] = BT[(kn * 3 + f) * 64 + lane];

        // s-outer / r-inner: 4 independent MFMAs between dependent pairs
#pragma unroll
        for (int ss = 0; ss < 3; ++ss)
#pragma unroll
            for (int r = 0; r < 4; ++r)
                acc[r] = __builtin_amdgcn_mfma_f32_32x32x16_bf16(
                    __builtin_bit_cast(bf16x8, F[r + ss]),
                    __builtin_bit_cast(bf16x8, B0[ss]), acc[r], 0, 0, 0);

#pragma unroll
        for (int f = 0; f < 6; ++f) F[f] = FN[f];
#pragma unroll
        for (int f = 0; f < 3; ++f) B0[f] = BN[f];
    }
#pragma unroll
    for (int ss = 0; ss < 3; ++ss)
#pragma unroll
        for (int r = 0; r < 4; ++r)
            acc[r] = __builtin_amdgcn_mfma_f32_32x32x16_bf16(
                __builtin_bit_cast(bf16x8, F[r + ss]),
                __builtin_bit_cast(bf16x8, B0[ss]), acc[r], 0, 0, 0);

    // ---- epilogue: per-wave LDS transpose, combine k4 shifts (barrier-free)
    float* Ew = E[wv];
    for (int r = 0; r < 4; ++r) {
        if (wv == 3 && r == 3) continue;
#pragma unroll
        for (int gq = 0; gq < 4; ++gq)
#pragma unroll
            for (int r4 = 0; r4 < 4; ++r4)
                Ew[m * 33 + 4 * hl + 8 * gq + r4] = acc[r][gq * 4 + r4];

        const int h2 = rbase + r;
        if (LAYER <= 1) {
            char* pl = (char*)outp + ((size_t)b * 900 + h1 * S + w1i) * PLANE
                       + (size_t)(h2 + 1) * 1024;
            const int t = lane >> 1, h8 = lane & 1;
            if (t < 30) {
                u32 wo[4];
#pragma unroll
                for (int p = 0; p < 4; ++p) {
                    const int c0 = 8 * h8 + 2 * p, c1 = c0 + 1;
                    float v0 = 0.f, v1 = 0.f;
                    if (c0 < 10)
                        v0 = fmaxf(Ew[c0 * 33 + t] + Ew[(10 + c0) * 33 + t + 1]
                                 + Ew[(20 + c0) * 33 + t + 2] + bias[c0], 0.f);
                    if (c1 < 10)
                        v1 = fmaxf(Ew[c1 * 33 + t] + Ew[(10 + c1) * 33 + t + 1]
                                 + Ew[(20 + c1) * 33 + t + 2] + bias[c1], 0.f);
                    wo[p] = (u32)f2bf(v0) | ((u32)f2bf(v1) << 16);
                }
                *(uint4*)(pl + (t + 1) * 32 + h8 * 16) =
                    make_uint4(wo[0], wo[1], wo[2], wo[3]);
            }
        } else {
            if (lane < 30) {
                const int t = lane;
                float v = Ew[t] + Ew[330 + t + 1] + Ew[660 + t + 2] + bias[0];
                v = fmaxf(v, 0.f);
                float* o = (float*)outp + (size_t)b * S4
                           + (size_t)(h1 * S + w1i) * 900 + h2 * 30 + t;
                if (ACCUM) *o += v; else *o = v;
            }
        }
    }
}

// ---------------------------------------------------------------------------
extern "C" void kernel_launch(void* const* d_in, const int* in_sizes, int n_in,
                              void* d_out, int out_size, void* d_ws, size_t ws_size,
                              hipStream_t stream)
{
    const float* x   = (const float*)d_in[0];
    const float* w1p = (const float*)d_in[1];
    const float* b1p = (const float*)d_in[2];
    const float* w2p = (const float*)d_in[3];
    const float* b2p = (const float*)d_in[4];
    const float* w3p = (const float*)d_in[5];
    const float* b3p = (const float*)d_in[6];
    float* out = (float*)d_out;

    // ws: fragtab (6*27*64 + 2*3*64) uint4 = 172032 B | y1 59 MB | y2 59 MB
    u32* ft = (u32*)d_ws;
    const uint4* ftL0 = (const uint4*)d_ws + 6 * 27 * 64;
    u16* y1 = (u16*)((char*)d_ws + 172032);
    u16* y2 = (u16*)((char*)y1 + YBYTES);

    prep_k<<<1842, 256, 0, stream>>>(ft, w1p, w2p, w3p, y1, y2);

    dim3 grid(S, S, 4), blk(256);
    for (int br = 0; br < 2; ++br) {
        const u32* f2 = ft + (size_t)(2 + br) * 27 * 64 * 4;
        const u32* f3 = ft + (size_t)(4 + br) * 27 * 64 * 4;
        conv0_k<<<grid, blk, 0, stream>>>(x, ftL0 + br * 192, b1p, (void*)y1);
        conv_k<1, false><<<grid, blk, 0, stream>>>(y1, f2, b2p, (void*)y2);
        if (br == 0)
            conv_k<2, false><<<grid, blk, 0, stream>>>(y2, f3, b3p, (void*)out);
        else
            conv_k<2, true><<<grid, blk, 0, stream>>>(y2, f3, b3p, (void*)out);
    }
}

// Round 16
// 375.011 us; speedup vs baseline: 1.2211x; 1.0241x over previous
//
#include <hip/hip_runtime.h>

// 4D conv net, MI355X. S=30, B=2, ch 1->10->10->1, kernel 3^4, pad 1, ReLU.
// out = net(x,w) + net(x,w_swap), w_swap has (k1,k2)<->(k3,k4).
// R7-R17: 32x32x16 bf16 MFMA, XCD-chunk swizzle, B-table in LDS, rotate-A
// depth-1 prefetch, barrier-free per-wave epilogue. conv_k = 69.5 us.
// R22 (champion, 384 us): R17 kernels + fused prep.
// R23: per-dispatch cost model dur ~= 40us base + 3.3us/tap (conv0 with
// 1/9 the work runs ~40us) -> ~240us of 384 is duplicated fixed cost.
// Merge branch endpoints: L0ab (x-fragments loaded ONCE, branch-invariant;
// 2x12 MFMAs -> y1a,y1b) and L2ab (both branches' taps, epilogue-a stashed
// in regs, SINGLE out store - kills the RMW). 7 dispatches -> 5.
// Needs 3 y-buffers (y2b aliases dead y1a): 177 MB. RUNTIME-GATED on
// ws_size; fallback = exact R22 path (no risk).

static constexpr int S  = 30;
static constexpr long S4 = 810000;
static constexpr size_t PLANE = 32768;                  // 32*32*16*2 B
static constexpr size_t YBYTES = (size_t)1800 * PLANE;  // [b(2)][g1][g2]

typedef __bf16 bf16x8 __attribute__((ext_vector_type(8)));
typedef float  f32x16 __attribute__((ext_vector_type(16)));
typedef unsigned int  u32;
typedef unsigned short u16;

static __device__ __forceinline__ u16 f2bf(float f) {
    u32 u = __builtin_bit_cast(u32, f);
    return (u16)((u + 0x7fffu + ((u >> 16) & 1u)) >> 16);
}

// ---------------------------------------------------------------------------
// Fused prep: blocks 0..41 build the B-fragment tables (42*256 = 10752 ids
// exactly); blocks 42..1841 zero halo positions of up to 3 y-buffers.
// Main table: [set(6)][k12(9)][k3(3)][lane(64)] uint4 (sets 0/1 unused).
// L0-packed (appended): [branch(2)][k3(3)][lane(64)] uint4.
__global__ __launch_bounds__(256) void prep_k(u32* __restrict__ ft,
    const float* __restrict__ w1, const float* __restrict__ w2,
    const float* __restrict__ w3, u16* __restrict__ p1,
    u16* __restrict__ p2, u16* __restrict__ p3)
{
    const int tid = threadIdx.x;
    if (blockIdx.x >= 42) {                    // ---- zero role ----
        const int pb = blockIdx.x - 42;
        if (tid >= 124) return;
        int hp, tp;
        if (tid < 32)      { hp = 0;        tp = tid; }
        else if (tid < 64) { hp = 31;       tp = tid - 32; }
        else if (tid < 94) { hp = tid - 63; tp = 0; }
        else               { hp = tid - 93; tp = 31; }
        const size_t off = (size_t)pb * PLANE + hp * 1024 + tp * 32;
        const uint4 z = make_uint4(0, 0, 0, 0);
        *(uint4*)((char*)p1 + off)      = z;
        *(uint4*)((char*)p1 + off + 16) = z;
        *(uint4*)((char*)p2 + off)      = z;
        *(uint4*)((char*)p2 + off + 16) = z;
        *(uint4*)((char*)p3 + off)      = z;
        *(uint4*)((char*)p3 + off + 16) = z;
        return;
    }
    // ---- fragprep role ----
    const int gid = blockIdx.x * 256 + tid;    // 0..10751
    const int lane = gid & 63;
    const int n = lane & 31, hl = lane >> 5;
    u16 us[8];
#pragma unroll
    for (int j = 0; j < 8; ++j) us[j] = 0;

    if (gid < 6 * 27 * 64) {
        int r = gid >> 6;
        const int k3 = r % 3; r /= 3;
        const int k12 = r % 9; const int set = r / 9;
        const int layer = set >> 1, swap = set & 1;
        const int k1 = k12 / 3, k2 = k12 % 3;
        if (n < 30) {
            const int k4 = (n < 10) ? 0 : ((n < 20) ? 1 : 2);
            const int co = n - 10 * k4;
            const int i1 = swap ? k3 : k1, i2 = swap ? k4 : k2;
            const int i3 = swap ? k1 : k3, i4 = swap ? k2 : k4;
            const int widx = ((i1 * 3 + i2) * 3 + i3) * 3 + i4;
#pragma unroll
            for (int j = 0; j < 8; ++j) {
                const int k = hl * 8 + j;
                float wv = 0.f;
                if (layer == 0) { if (k == 0) wv = w1[co * 81 + widx]; }
                else if (layer == 1) { if (k < 10) wv = w2[(co * 10 + k) * 81 + widx]; }
                else { if (k < 10 && co == 0) wv = w3[k * 81 + widx]; }
                us[j] = f2bf(wv);
            }
        }
    } else {
        const int idx = gid - 6 * 27 * 64;       // 0..383
        int r = idx >> 6;                        // 0..5
        const int k3 = r % 3, swap = r / 3;
        if (n < 30) {
            const int k4 = (n < 10) ? 0 : ((n < 20) ? 1 : 2);
            const int co = n - 10 * k4;
#pragma unroll
            for (int j = 0; j < 8; ++j) {
                const int k12 = hl * 8 + j;
                if (k12 < 9) {
                    const int k1 = k12 / 3, k2 = k12 % 3;
                    const int i1 = swap ? k3 : k1, i2 = swap ? k4 : k2;
                    const int i3 = swap ? k1 : k3, i4 = swap ? k2 : k4;
                    const int widx = ((i1 * 3 + i2) * 3 + i3) * 3 + i4;
                    us[j] = f2bf(w1[co * 81 + widx]);
                }
            }
        }
    }
    u32* o = ft + (size_t)gid * 4;
    o[0] = (u32)us[0] | ((u32)us[1] << 16);
    o[1] = (u32)us[2] | ((u32)us[3] << 16);
    o[2] = (u32)us[4] | ((u32)us[5] << 16);
    o[3] = (u32)us[6] | ((u32)us[7] << 16);
}

// ---------------------------------------------------------------------------
// Common L0 A-fragment build + epilogue as device helpers.
static __device__ __forceinline__ void l0_frags(
    const float* __restrict__ x, int b, int h1, int w1i, int rbase,
    int m, int hl, uint4* F)
{
    int gof[9]; int gokm = 0;
#pragma unroll
    for (int k12 = 0; k12 < 9; ++k12) {
        const int g1 = h1 + k12 / 3 - 1, g2 = w1i + k12 % 3 - 1;
        gof[k12] = 0;
        if (g1 >= 0 && g1 < S && g2 >= 0 && g2 < S) {
            gof[k12] = (g1 * S + g2) * 900; gokm |= 1 << k12;
        }
    }
    const float* xb = x + (size_t)b * S4;
#pragma unroll
    for (int f = 0; f < 6; ++f) {
        const int hp = rbase + f;
        const bool rk = (hp >= 1 && hp <= 30 && m >= 1 && m <= 30);
        const int ro = (hp - 1) * 30 + (m - 1);
        u16 av[8];
#pragma unroll
        for (int j = 0; j < 8; ++j) av[j] = 0;
        if (hl == 0) {
#pragma unroll
            for (int j = 0; j < 8; ++j) {
                float v = 0.f;
                if (rk && ((gokm >> j) & 1)) v = xb[gof[j] + ro];
                av[j] = f2bf(v);
            }
        } else {
            float v = 0.f;
            if (rk && ((gokm >> 8) & 1)) v = xb[gof[8] + ro];
            av[0] = f2bf(v);
        }
        F[f] = make_uint4((u32)av[0] | ((u32)av[1] << 16),
                          (u32)av[2] | ((u32)av[3] << 16),
                          (u32)av[4] | ((u32)av[5] << 16),
                          (u32)av[6] | ((u32)av[7] << 16));
    }
}

static __device__ __forceinline__ void plane_epilogue(
    float* Ew, const f32x16* acc, const float* __restrict__ bias,
    void* __restrict__ outp, int b, int h1, int w1i, int rbase,
    int m, int hl, int lane, int wv)
{
    for (int r = 0; r < 4; ++r) {
        if (wv == 3 && r == 3) continue;
#pragma unroll
        for (int gq = 0; gq < 4; ++gq)
#pragma unroll
            for (int r4 = 0; r4 < 4; ++r4)
                Ew[m * 33 + 4 * hl + 8 * gq + r4] = acc[r][gq * 4 + r4];

        const int h2 = rbase + r;
        char* pl = (char*)outp + ((size_t)b * 900 + h1 * S + w1i) * PLANE
                   + (size_t)(h2 + 1) * 1024;
        const int t = lane >> 1, h8 = lane & 1;
        if (t < 30) {
            u32 wo[4];
#pragma unroll
            for (int p = 0; p < 4; ++p) {
                const int c0 = 8 * h8 + 2 * p, c1 = c0 + 1;
                float v0 = 0.f, v1 = 0.f;
                if (c0 < 10)
                    v0 = fmaxf(Ew[c0 * 33 + t] + Ew[(10 + c0) * 33 + t + 1]
                             + Ew[(20 + c0) * 33 + t + 2] + bias[c0], 0.f);
                if (c1 < 10)
                    v1 = fmaxf(Ew[c1 * 33 + t] + Ew[(10 + c1) * 33 + t + 1]
                             + Ew[(20 + c1) * 33 + t + 2] + bias[c1], 0.f);
                wo[p] = (u32)f2bf(v0) | ((u32)f2bf(v1) << 16);
            }
            *(uint4*)(pl + (t + 1) * 32 + h8 * 16) =
                make_uint4(wo[0], wo[1], wo[2], wo[3]);
        }
    }
}

// ---------------------------------------------------------------------------
// Layer 0, single branch (R13, fallback path).
__global__ __launch_bounds__(256, 4) void conv0_k(
    const float* __restrict__ x, const uint4* __restrict__ bt,
    const float* __restrict__ bias, void* __restrict__ outp)
{
    __shared__ float E[4][1056];
    const int wgid = blockIdx.x + S * blockIdx.y + 900 * blockIdx.z;
    const int id2  = (wgid & 7) * 450 + (wgid >> 3);
    const int half = id2 & 1;
    int sp = id2 >> 1;
    const int w1i = sp % S; sp /= S;
    const int h1  = sp % S;
    const int b   = sp / S;
    const int tid = threadIdx.x;
    const int lane = tid & 63, wv = tid >> 6;
    const int m = lane & 31, hl = lane >> 5;
    const int rbase = half * 15 + wv * 4;

    uint4 Bs[3];
#pragma unroll
    for (int ss = 0; ss < 3; ++ss) Bs[ss] = bt[ss * 64 + lane];

    uint4 F[6];
    l0_frags(x, b, h1, w1i, rbase, m, hl, F);

    f32x16 acc[4];
#pragma unroll
    for (int r = 0; r < 4; ++r)
#pragma unroll
        for (int e = 0; e < 16; ++e) acc[r][e] = 0.f;
#pragma unroll
    for (int ss = 0; ss < 3; ++ss)
#pragma unroll
        for (int r = 0; r < 4; ++r)
            acc[r] = __builtin_amdgcn_mfma_f32_32x32x16_bf16(
                __builtin_bit_cast(bf16x8, F[r + ss]),
                __builtin_bit_cast(bf16x8, Bs[ss]), acc[r], 0, 0, 0);

    plane_epilogue(E[wv], acc, bias, outp, b, h1, w1i, rbase, m, hl, lane, wv);
}

// ---------------------------------------------------------------------------
// Layer 0, BOTH branches (merged path): x-fragments loaded once, two MFMA
// sets, two epilogues (y1a, y1b).
__global__ __launch_bounds__(256, 2) void conv0ab_k(
    const float* __restrict__ x, const uint4* __restrict__ bt,
    const float* __restrict__ bias, void* __restrict__ y1a,
    void* __restrict__ y1b)
{
    __shared__ float E[4][1056];
    const int wgid = blockIdx.x + S * blockIdx.y + 900 * blockIdx.z;
    const int id2  = (wgid & 7) * 450 + (wgid >> 3);
    const int half = id2 & 1;
    int sp = id2 >> 1;
    const int w1i = sp % S; sp /= S;
    const int h1  = sp % S;
    const int b   = sp / S;
    const int tid = threadIdx.x;
    const int lane = tid & 63, wv = tid >> 6;
    const int m = lane & 31, hl = lane >> 5;
    const int rbase = half * 15 + wv * 4;

    uint4 F[6];
    l0_frags(x, b, h1, w1i, rbase, m, hl, F);

    f32x16 acc[4];
    // ---- branch 0 ----
    {
        uint4 Bs[3];
#pragma unroll
        for (int ss = 0; ss < 3; ++ss) Bs[ss] = bt[ss * 64 + lane];
#pragma unroll
        for (int r = 0; r < 4; ++r)
#pragma unroll
            for (int e = 0; e < 16; ++e) acc[r][e] = 0.f;
#pragma unroll
        for (int ss = 0; ss < 3; ++ss)
#pragma unroll
            for (int r = 0; r < 4; ++r)
                acc[r] = __builtin_amdgcn_mfma_f32_32x32x16_bf16(
                    __builtin_bit_cast(bf16x8, F[r + ss]),
                    __builtin_bit_cast(bf16x8, Bs[ss]), acc[r], 0, 0, 0);
        plane_epilogue(E[wv], acc, bias, y1a, b, h1, w1i, rbase, m, hl, lane, wv);
    }
    // ---- branch 1 ----
    {
        uint4 Bs[3];
#pragma unroll
        for (int ss = 0; ss < 3; ++ss) Bs[ss] = bt[192 + ss * 64 + lane];
#pragma unroll
        for (int r = 0; r < 4; ++r)
#pragma unroll
            for (int e = 0; e < 16; ++e) acc[r][e] = 0.f;
#pragma unroll
        for (int ss = 0; ss < 3; ++ss)
#pragma unroll
            for (int r = 0; r < 4; ++r)
                acc[r] = __builtin_amdgcn_mfma_f32_32x32x16_bf16(
                    __builtin_bit_cast(bf16x8, F[r + ss]),
                    __builtin_bit_cast(bf16x8, Bs[ss]), acc[r], 0, 0, 0);
        plane_epilogue(E[wv], acc, bias, y1b, b, h1, w1i, rbase, m, hl, lane, wv);
    }
}

// ---------------------------------------------------------------------------
// Layers 1/2 (R17, byte-identical): B-table staged to LDS, rotate-A depth-1
// prefetch, barrier-free per-wave epilogue, launch_bounds(256,2).
template<int LAYER, bool ACCUM>
__global__ __launch_bounds__(256, 2) void conv_k(
    const void* __restrict__ inp, const u32* __restrict__ ftab,
    const float* __restrict__ bias, void* __restrict__ outp)
{
    __shared__ float E[4][1056];
    __shared__ uint4 BT[1728];

    const int tid = threadIdx.x;
    {
        const uint4* g = (const uint4*)ftab;
#pragma unroll
        for (int j = 0; j < 7; ++j) {
            const int idx = j * 256 + tid;
            if (idx < 1728) BT[idx] = g[idx];
        }
    }
    __syncthreads();

    const int wgid = blockIdx.x + S * blockIdx.y + 900 * blockIdx.z;
    const int id2  = (wgid & 7) * 450 + (wgid >> 3);
    const int half = id2 & 1;
    int sp = id2 >> 1;
    const int w1i = sp % S; sp /= S;
    const int h1  = sp % S;
    const int b   = sp / S;

    const int lane = tid & 63, wv = tid >> 6;
    const int m = lane & 31, hl = lane >> 5;
    const int rbase = half * 15 + wv * 4;

    int rofs[6];
#pragma unroll
    for (int f = 0; f < 6; ++f) {
        int rr = rbase + f; if (rr > 31) rr = 31;
        rofs[f] = rr * 1024;
    }

    int kl[9], nk = 0;
#pragma unroll
    for (int k12 = 0; k12 < 9; ++k12) {
        const int g1 = h1 + k12 / 3 - 1, g2 = w1i + k12 % 3 - 1;
        if (g1 >= 0 && g1 < S && g2 >= 0 && g2 < S)
            kl[nk++] = (g1 * S + g2) | (k12 << 10);
    }

    f32x16 acc[4];
#pragma unroll
    for (int r = 0; r < 4; ++r)
#pragma unroll
        for (int e = 0; e < 16; ++e) acc[r][e] = 0.f;

    auto loadA = [&](uint4* Fd, int g) {
        const char* P = (const char*)inp + ((size_t)b * 900 + g) * PLANE
                        + m * 32 + hl * 16;
#pragma unroll
        for (int f = 0; f < 6; ++f)
            Fd[f] = *(const uint4*)(P + rofs[f]);
    };

    uint4 B0[3];
    {
        const int k0 = kl[0] >> 10;
#pragma unroll
        for (int f = 0; f < 3; ++f) B0[f] = BT[(k0 * 3 + f) * 64 + lane];
    }
    uint4 F[6];
    loadA(F, kl[0] & 1023);

    for (int ki = 0; ki + 1 < nk; ++ki) {
        const int gn = kl[ki + 1] & 1023, kn = kl[ki + 1] >> 10;
        uint4 FN[6];
        loadA(FN, gn);
        uint4 BN[3];
#pragma unroll
        for (int f = 0; f < 3; ++f) BN[f] = BT[(kn * 3 + f) * 64 + lane];

#pragma unroll
        for (int ss = 0; ss < 3; ++ss)
#pragma unroll
            for (int r = 0; r < 4; ++r)
                acc[r] = __builtin_amdgcn_mfma_f32_32x32x16_bf16(
                    __builtin_bit_cast(bf16x8, F[r + ss]),
                    __builtin_bit_cast(bf16x8, B0[ss]), acc[r], 0, 0, 0);

#pragma unroll
        for (int f = 0; f < 6; ++f) F[f] = FN[f];
#pragma unroll
        for (int f = 0; f < 3; ++f) B0[f] = BN[f];
    }
#pragma unroll
    for (int ss = 0; ss < 3; ++ss)
#pragma unroll
        for (int r = 0; r < 4; ++r)
            acc[r] = __builtin_amdgcn_mfma_f32_32x32x16_bf16(
                __builtin_bit_cast(bf16x8, F[r + ss]),
                __builtin_bit_cast(bf16x8, B0[ss]), acc[r], 0, 0, 0);

    float* Ew = E[wv];
    for (int r = 0; r < 4; ++r) {
        if (wv == 3 && r == 3) continue;
#pragma unroll
        for (int gq = 0; gq < 4; ++gq)
#pragma unroll
            for (int r4 = 0; r4 < 4; ++r4)
                Ew[m * 33 + 4 * hl + 8 * gq + r4] = acc[r][gq * 4 + r4];

        const int h2 = rbase + r;
        if (LAYER <= 1) {
            char* pl = (char*)outp + ((size_t)b * 900 + h1 * S + w1i) * PLANE
                       + (size_t)(h2 + 1) * 1024;
            const int t = lane >> 1, h8 = lane & 1;
            if (t < 30) {
                u32 wo[4];
#pragma unroll
                for (int p = 0; p < 4; ++p) {
                    const int c0 = 8 * h8 + 2 * p, c1 = c0 + 1;
                    float v0 = 0.f, v1 = 0.f;
                    if (c0 < 10)
                        v0 = fmaxf(Ew[c0 * 33 + t] + Ew[(10 + c0) * 33 + t + 1]
                                 + Ew[(20 + c0) * 33 + t + 2] + bias[c0], 0.f);
                    if (c1 < 10)
                        v1 = fmaxf(Ew[c1 * 33 + t] + Ew[(10 + c1) * 33 + t + 1]
                                 + Ew[(20 + c1) * 33 + t + 2] + bias[c1], 0.f);
                    wo[p] = (u32)f2bf(v0) | ((u32)f2bf(v1) << 16);
                }
                *(uint4*)(pl + (t + 1) * 32 + h8 * 16) =
                    make_uint4(wo[0], wo[1], wo[2], wo[3]);
            }
        } else {
            if (lane < 30) {
                const int t = lane;
                float v = Ew[t] + Ew[330 + t + 1] + Ew[660 + t + 2] + bias[0];
                v = fmaxf(v, 0.f);
                float* o = (float*)outp + (size_t)b * S4
                           + (size_t)(h1 * S + w1i) * 900 + h2 * 30 + t;
                if (ACCUM) *o += v; else *o = v;
            }
        }
    }
}

// ---------------------------------------------------------------------------
// Layer 2, BOTH branches (merged path): taps over y2a then y2b; epilogue-a
// stashed in registers; single out store (no RMW). LDS: both B-tables
// (55.3 KB); E overlays dead BT[0] behind a barrier after taps-a.
__global__ __launch_bounds__(256, 2) void conv2ab_k(
    const void* __restrict__ y2a, const void* __restrict__ y2b,
    const u32* __restrict__ fta, const u32* __restrict__ ftb,
    const float* __restrict__ bias, float* __restrict__ out)
{
    __shared__ uint4 BTS[2][1728];        // branch tables; E overlays BTS[0]

    const int tid = threadIdx.x;
    {
        const uint4* ga = (const uint4*)fta;
        const uint4* gb = (const uint4*)ftb;
#pragma unroll
        for (int j = 0; j < 7; ++j) {
            const int idx = j * 256 + tid;
            if (idx < 1728) { BTS[0][idx] = ga[idx]; BTS[1][idx] = gb[idx]; }
        }
    }
    __syncthreads();

    const int wgid = blockIdx.x + S * blockIdx.y + 900 * blockIdx.z;
    const int id2  = (wgid & 7) * 450 + (wgid >> 3);
    const int half = id2 & 1;
    int sp = id2 >> 1;
    const int w1i = sp % S; sp /= S;
    const int h1  = sp % S;
    const int b   = sp / S;

    const int lane = tid & 63, wv = tid >> 6;
    const int m = lane & 31, hl = lane >> 5;
    const int rbase = half * 15 + wv * 4;

    int rofs[6];
#pragma unroll
    for (int f = 0; f < 6; ++f) {
        int rr = rbase + f; if (rr > 31) rr = 31;
        rofs[f] = rr * 1024;
    }

    int kl[9], nk = 0;
#pragma unroll
    for (int k12 = 0; k12 < 9; ++k12) {
        const int g1 = h1 + k12 / 3 - 1, g2 = w1i + k12 % 3 - 1;
        if (g1 >= 0 && g1 < S && g2 >= 0 && g2 < S)
            kl[nk++] = (g1 * S + g2) | (k12 << 10);
    }

    f32x16 acc[4];

    auto run_taps = [&](const void* inp, const uint4* BTb) {
#pragma unroll
        for (int r = 0; r < 4; ++r)
#pragma unroll
            for (int e = 0; e < 16; ++e) acc[r][e] = 0.f;
        auto loadA = [&](uint4* Fd, int g) {
            const char* P = (const char*)inp + ((size_t)b * 900 + g) * PLANE
                            + m * 32 + hl * 16;
#pragma unroll
            for (int f = 0; f < 6; ++f)
                Fd[f] = *(const uint4*)(P + rofs[f]);
        };
        uint4 B0[3];
        {
            const int k0 = kl[0] >> 10;
#pragma unroll
            for (int f = 0; f < 3; ++f) B0[f] = BTb[(k0 * 3 + f) * 64 + lane];
        }
        uint4 F[6];
        loadA(F, kl[0] & 1023);
        for (int ki = 0; ki + 1 < nk; ++ki) {
            const int gn = kl[ki + 1] & 1023, kn = kl[ki + 1] >> 10;
            uint4 FN[6];
            loadA(FN, gn);
            uint4 BN[3];
#pragma unroll
            for (int f = 0; f < 3; ++f) BN[f] = BTb[(kn * 3 + f) * 64 + lane];
#pragma unroll
            for (int ss = 0; ss < 3; ++ss)
#pragma unroll
                for (int r = 0; r < 4; ++r)
                    acc[r] = __builtin_amdgcn_mfma_f32_32x32x16_bf16(
                        __builtin_bit_cast(bf16x8, F[r + ss]),
                        __builtin_bit_cast(bf16x8, B0[ss]), acc[r], 0, 0, 0);
#pragma unroll
            for (int f = 0; f < 6; ++f) F[f] = FN[f];
#pragma unroll
            for (int f = 0; f < 3; ++f) B0[f] = BN[f];
        }
#pragma unroll
        for (int ss = 0; ss < 3; ++ss)
#pragma unroll
            for (int r = 0; r < 4; ++r)
                acc[r] = __builtin_amdgcn_mfma_f32_32x32x16_bf16(
                    __builtin_bit_cast(bf16x8, F[r + ss]),
                    __builtin_bit_cast(bf16x8, B0[ss]), acc[r], 0, 0, 0);
    };

    // ---- branch 0 taps ----
    run_taps(y2a, BTS[0]);
    __syncthreads();                      // all waves done with BTS[0]
    float* Ew = (float*)&BTS[0][0] + wv * 1056;   // E overlays dead BTS[0]

    float va[4] = {0.f, 0.f, 0.f, 0.f};
    for (int r = 0; r < 4; ++r) {
        if (wv == 3 && r == 3) continue;
#pragma unroll
        for (int gq = 0; gq < 4; ++gq)
#pragma unroll
            for (int r4 = 0; r4 < 4; ++r4)
                Ew[m * 33 + 4 * hl + 8 * gq + r4] = acc[r][gq * 4 + r4];
        if (lane < 30) {
            const int t = lane;
            va[r] = fmaxf(Ew[t] + Ew[330 + t + 1] + Ew[660 + t + 2] + bias[0], 0.f);
        }
    }

    // ---- branch 1 taps (BTS[1] untouched by E overlay) ----
    run_taps(y2b, BTS[1]);
    for (int r = 0; r < 4; ++r) {
        if (wv == 3 && r == 3) continue;
#pragma unroll
        for (int gq = 0; gq < 4; ++gq)
#pragma unroll
            for (int r4 = 0; r4 < 4; ++r4)
                Ew[m * 33 + 4 * hl + 8 * gq + r4] = acc[r][gq * 4 + r4];
        const int h2 = rbase + r;
        if (lane < 30) {
            const int t = lane;
            float v = fmaxf(Ew[t] + Ew[330 + t + 1] + Ew[660 + t + 2] + bias[0], 0.f);
            out[(size_t)b * S4 + (size_t)(h1 * S + w1i) * 900 + h2 * 30 + t]
                = va[r] + v;
        }
    }
}

// ---------------------------------------------------------------------------
extern "C" void kernel_launch(void* const* d_in, const int* in_sizes, int n_in,
                              void* d_out, int out_size, void* d_ws, size_t ws_size,
                              hipStream_t stream)
{
    const float* x   = (const float*)d_in[0];
    const float* w1p = (const float*)d_in[1];
    const float* b1p = (const float*)d_in[2];
    const float* w2p = (const float*)d_in[3];
    const float* b2p = (const float*)d_in[4];
    const float* w3p = (const float*)d_in[5];
    const float* b3p = (const float*)d_in[6];
    float* out = (float*)d_out;

    u32* ft = (u32*)d_ws;
    const uint4* ftL0 = (const uint4*)d_ws + 6 * 27 * 64;
    u16* y1a = (u16*)((char*)d_ws + 172032);
    u16* y1b = (u16*)((char*)y1a + YBYTES);
    u16* y2a = (u16*)((char*)y1b + YBYTES);

    const u32* f2b0 = ft + (size_t)2 * 27 * 64 * 4;
    const u32* f2b1 = ft + (size_t)3 * 27 * 64 * 4;
    const u32* f3b0 = ft + (size_t)4 * 27 * 64 * 4;
    const u32* f3b1 = ft + (size_t)5 * 27 * 64 * 4;

    dim3 grid(S, S, 4), blk(256);
    const size_t need = 172032 + 3 * YBYTES;

    if (ws_size >= need) {
        // Merged path: 5 dispatches. y2b aliases y1a (dead after L1a).
        u16* y2b = y1a;
        prep_k<<<1842, blk, 0, stream>>>(ft, w1p, w2p, w3p, y1a, y1b, y2a);
        conv0ab_k<<<grid, blk, 0, stream>>>(x, ftL0, b1p, (void*)y1a, (void*)y1b);
        conv_k<1, false><<<grid, blk, 0, stream>>>(y1a, f2b0, b2p, (void*)y2a);
        conv_k<1, false><<<grid, blk, 0, stream>>>(y1b, f2b1, b2p, (void*)y2b);
        conv2ab_k<<<grid, blk, 0, stream>>>(y2a, y2b, f3b0, f3b1, b3p, out);
    } else {
        // Fallback: exact R22 path (2 buffers: y1a, y1b-as-y2).
        u16* y1 = y1a;
        u16* y2 = y1b;
        prep_k<<<1842, blk, 0, stream>>>(ft, w1p, w2p, w3p, y1, y2, y2);
        for (int br = 0; br < 2; ++br) {
            const u32* f2 = (br == 0) ? f2b0 : f2b1;
            const u32* f3 = (br == 0) ? f3b0 : f3b1;
            conv0_k<<<grid, blk, 0, stream>>>(x, ftL0 + br * 192, b1p, (void*)y1);
            conv_k<1, false><<<grid, blk, 0, stream>>>(y1, f2, b2p, (void*)y2);
            if (br == 0)
                conv_k<2, false><<<grid, blk, 0, stream>>>(y2, f3, b3p, (void*)out);
            else
                conv_k<2, true><<<grid, blk, 0, stream>>>(y2, f3, b3p, (void*)out);
        }
    }
}

// Round 17
// 374.085 us; speedup vs baseline: 1.2241x; 1.0025x over previous
//
#include <hip/hip_runtime.h>

// 4D conv net, MI355X. S=30, B=2, ch 1->10->10->1, kernel 3^4, pad 1, ReLU.
// out = net(x,w) + net(x,w_swap), w_swap has (k1,k2)<->(k3,k4).
// R7-R17: 32x32x16 bf16 MFMA, XCD-chunk swizzle, B-table in LDS, rotate-A
// depth-1 prefetch, barrier-free per-wave epilogue. conv_k = 69.5 us.
// R22: R17 kernels + fused prep (384 us).
// R23 (375 us): branch-endpoint merges. conv0ab (x-frags loaded once),
// conv2ab (both branches' taps, reg-stashed epilogue-a, single out store:
// WRITE 81->6.3 MB). conv2ab FETCH 160 MB = dual-buffer L2 thrash, but
// net win (dispatch base + RMW savings > thrash).
// R24: merge the two INDEPENDENT L1 dispatches into one z=8 dispatch
// (branch = z>>2, zq = z&3). Unlike conv2ab, each block touches only its
// own branch's buffers, and z-slowest dispatch order keeps the branches
// temporally separated in L2 (no thrash); 3600%8==0 preserves per-branch
// XCD swizzle alignment. Captures the ramp/drain overlap of one dispatch
// boundary. 5 dispatches -> 4. Fallback (R22 path) untouched.

static constexpr int S  = 30;
static constexpr long S4 = 810000;
static constexpr size_t PLANE = 32768;                  // 32*32*16*2 B
static constexpr size_t YBYTES = (size_t)1800 * PLANE;  // [b(2)][g1][g2]

typedef __bf16 bf16x8 __attribute__((ext_vector_type(8)));
typedef float  f32x16 __attribute__((ext_vector_type(16)));
typedef unsigned int  u32;
typedef unsigned short u16;

static __device__ __forceinline__ u16 f2bf(float f) {
    u32 u = __builtin_bit_cast(u32, f);
    return (u16)((u + 0x7fffu + ((u >> 16) & 1u)) >> 16);
}

// ---------------------------------------------------------------------------
// Fused prep: blocks 0..41 build the B-fragment tables (42*256 = 10752 ids
// exactly); blocks 42..1841 zero halo positions of up to 3 y-buffers.
// Main table: [set(6)][k12(9)][k3(3)][lane(64)] uint4 (sets 0/1 unused).
// L0-packed (appended): [branch(2)][k3(3)][lane(64)] uint4.
__global__ __launch_bounds__(256) void prep_k(u32* __restrict__ ft,
    const float* __restrict__ w1, const float* __restrict__ w2,
    const float* __restrict__ w3, u16* __restrict__ p1,
    u16* __restrict__ p2, u16* __restrict__ p3)
{
    const int tid = threadIdx.x;
    if (blockIdx.x >= 42) {                    // ---- zero role ----
        const int pb = blockIdx.x - 42;
        if (tid >= 124) return;
        int hp, tp;
        if (tid < 32)      { hp = 0;        tp = tid; }
        else if (tid < 64) { hp = 31;       tp = tid - 32; }
        else if (tid < 94) { hp = tid - 63; tp = 0; }
        else               { hp = tid - 93; tp = 31; }
        const size_t off = (size_t)pb * PLANE + hp * 1024 + tp * 32;
        const uint4 z = make_uint4(0, 0, 0, 0);
        *(uint4*)((char*)p1 + off)      = z;
        *(uint4*)((char*)p1 + off + 16) = z;
        *(uint4*)((char*)p2 + off)      = z;
        *(uint4*)((char*)p2 + off + 16) = z;
        *(uint4*)((char*)p3 + off)      = z;
        *(uint4*)((char*)p3 + off + 16) = z;
        return;
    }
    // ---- fragprep role ----
    const int gid = blockIdx.x * 256 + tid;    // 0..10751
    const int lane = gid & 63;
    const int n = lane & 31, hl = lane >> 5;
    u16 us[8];
#pragma unroll
    for (int j = 0; j < 8; ++j) us[j] = 0;

    if (gid < 6 * 27 * 64) {
        int r = gid >> 6;
        const int k3 = r % 3; r /= 3;
        const int k12 = r % 9; const int set = r / 9;
        const int layer = set >> 1, swap = set & 1;
        const int k1 = k12 / 3, k2 = k12 % 3;
        if (n < 30) {
            const int k4 = (n < 10) ? 0 : ((n < 20) ? 1 : 2);
            const int co = n - 10 * k4;
            const int i1 = swap ? k3 : k1, i2 = swap ? k4 : k2;
            const int i3 = swap ? k1 : k3, i4 = swap ? k2 : k4;
            const int widx = ((i1 * 3 + i2) * 3 + i3) * 3 + i4;
#pragma unroll
            for (int j = 0; j < 8; ++j) {
                const int k = hl * 8 + j;
                float wv = 0.f;
                if (layer == 0) { if (k == 0) wv = w1[co * 81 + widx]; }
                else if (layer == 1) { if (k < 10) wv = w2[(co * 10 + k) * 81 + widx]; }
                else { if (k < 10 && co == 0) wv = w3[k * 81 + widx]; }
                us[j] = f2bf(wv);
            }
        }
    } else {
        const int idx = gid - 6 * 27 * 64;       // 0..383
        int r = idx >> 6;                        // 0..5
        const int k3 = r % 3, swap = r / 3;
        if (n < 30) {
            const int k4 = (n < 10) ? 0 : ((n < 20) ? 1 : 2);
            const int co = n - 10 * k4;
#pragma unroll
            for (int j = 0; j < 8; ++j) {
                const int k12 = hl * 8 + j;
                if (k12 < 9) {
                    const int k1 = k12 / 3, k2 = k12 % 3;
                    const int i1 = swap ? k3 : k1, i2 = swap ? k4 : k2;
                    const int i3 = swap ? k1 : k3, i4 = swap ? k2 : k4;
                    const int widx = ((i1 * 3 + i2) * 3 + i3) * 3 + i4;
                    us[j] = f2bf(w1[co * 81 + widx]);
                }
            }
        }
    }
    u32* o = ft + (size_t)gid * 4;
    o[0] = (u32)us[0] | ((u32)us[1] << 16);
    o[1] = (u32)us[2] | ((u32)us[3] << 16);
    o[2] = (u32)us[4] | ((u32)us[5] << 16);
    o[3] = (u32)us[6] | ((u32)us[7] << 16);
}

// ---------------------------------------------------------------------------
// Common L0 A-fragment build + epilogue as device helpers.
static __device__ __forceinline__ void l0_frags(
    const float* __restrict__ x, int b, int h1, int w1i, int rbase,
    int m, int hl, uint4* F)
{
    int gof[9]; int gokm = 0;
#pragma unroll
    for (int k12 = 0; k12 < 9; ++k12) {
        const int g1 = h1 + k12 / 3 - 1, g2 = w1i + k12 % 3 - 1;
        gof[k12] = 0;
        if (g1 >= 0 && g1 < S && g2 >= 0 && g2 < S) {
            gof[k12] = (g1 * S + g2) * 900; gokm |= 1 << k12;
        }
    }
    const float* xb = x + (size_t)b * S4;
#pragma unroll
    for (int f = 0; f < 6; ++f) {
        const int hp = rbase + f;
        const bool rk = (hp >= 1 && hp <= 30 && m >= 1 && m <= 30);
        const int ro = (hp - 1) * 30 + (m - 1);
        u16 av[8];
#pragma unroll
        for (int j = 0; j < 8; ++j) av[j] = 0;
        if (hl == 0) {
#pragma unroll
            for (int j = 0; j < 8; ++j) {
                float v = 0.f;
                if (rk && ((gokm >> j) & 1)) v = xb[gof[j] + ro];
                av[j] = f2bf(v);
            }
        } else {
            float v = 0.f;
            if (rk && ((gokm >> 8) & 1)) v = xb[gof[8] + ro];
            av[0] = f2bf(v);
        }
        F[f] = make_uint4((u32)av[0] | ((u32)av[1] << 16),
                          (u32)av[2] | ((u32)av[3] << 16),
                          (u32)av[4] | ((u32)av[5] << 16),
                          (u32)av[6] | ((u32)av[7] << 16));
    }
}

static __device__ __forceinline__ void plane_epilogue(
    float* Ew, const f32x16* acc, const float* __restrict__ bias,
    void* __restrict__ outp, int b, int h1, int w1i, int rbase,
    int m, int hl, int lane, int wv)
{
    for (int r = 0; r < 4; ++r) {
        if (wv == 3 && r == 3) continue;
#pragma unroll
        for (int gq = 0; gq < 4; ++gq)
#pragma unroll
            for (int r4 = 0; r4 < 4; ++r4)
                Ew[m * 33 + 4 * hl + 8 * gq + r4] = acc[r][gq * 4 + r4];

        const int h2 = rbase + r;
        char* pl = (char*)outp + ((size_t)b * 900 + h1 * S + w1i) * PLANE
                   + (size_t)(h2 + 1) * 1024;
        const int t = lane >> 1, h8 = lane & 1;
        if (t < 30) {
            u32 wo[4];
#pragma unroll
            for (int p = 0; p < 4; ++p) {
                const int c0 = 8 * h8 + 2 * p, c1 = c0 + 1;
                float v0 = 0.f, v1 = 0.f;
                if (c0 < 10)
                    v0 = fmaxf(Ew[c0 * 33 + t] + Ew[(10 + c0) * 33 + t + 1]
                             + Ew[(20 + c0) * 33 + t + 2] + bias[c0], 0.f);
                if (c1 < 10)
                    v1 = fmaxf(Ew[c1 * 33 + t] + Ew[(10 + c1) * 33 + t + 1]
                             + Ew[(20 + c1) * 33 + t + 2] + bias[c1], 0.f);
                wo[p] = (u32)f2bf(v0) | ((u32)f2bf(v1) << 16);
            }
            *(uint4*)(pl + (t + 1) * 32 + h8 * 16) =
                make_uint4(wo[0], wo[1], wo[2], wo[3]);
        }
    }
}

// ---------------------------------------------------------------------------
// Layer 0, single branch (R13, fallback path).
__global__ __launch_bounds__(256, 4) void conv0_k(
    const float* __restrict__ x, const uint4* __restrict__ bt,
    const float* __restrict__ bias, void* __restrict__ outp)
{
    __shared__ float E[4][1056];
    const int wgid = blockIdx.x + S * blockIdx.y + 900 * blockIdx.z;
    const int id2  = (wgid & 7) * 450 + (wgid >> 3);
    const int half = id2 & 1;
    int sp = id2 >> 1;
    const int w1i = sp % S; sp /= S;
    const int h1  = sp % S;
    const int b   = sp / S;
    const int tid = threadIdx.x;
    const int lane = tid & 63, wv = tid >> 6;
    const int m = lane & 31, hl = lane >> 5;
    const int rbase = half * 15 + wv * 4;

    uint4 Bs[3];
#pragma unroll
    for (int ss = 0; ss < 3; ++ss) Bs[ss] = bt[ss * 64 + lane];

    uint4 F[6];
    l0_frags(x, b, h1, w1i, rbase, m, hl, F);

    f32x16 acc[4];
#pragma unroll
    for (int r = 0; r < 4; ++r)
#pragma unroll
        for (int e = 0; e < 16; ++e) acc[r][e] = 0.f;
#pragma unroll
    for (int ss = 0; ss < 3; ++ss)
#pragma unroll
        for (int r = 0; r < 4; ++r)
            acc[r] = __builtin_amdgcn_mfma_f32_32x32x16_bf16(
                __builtin_bit_cast(bf16x8, F[r + ss]),
                __builtin_bit_cast(bf16x8, Bs[ss]), acc[r], 0, 0, 0);

    plane_epilogue(E[wv], acc, bias, outp, b, h1, w1i, rbase, m, hl, lane, wv);
}

// ---------------------------------------------------------------------------
// Layer 0, BOTH branches (merged path): x-fragments loaded once, two MFMA
// sets, two epilogues (y1a, y1b).
__global__ __launch_bounds__(256, 2) void conv0ab_k(
    const float* __restrict__ x, const uint4* __restrict__ bt,
    const float* __restrict__ bias, void* __restrict__ y1a,
    void* __restrict__ y1b)
{
    __shared__ float E[4][1056];
    const int wgid = blockIdx.x + S * blockIdx.y + 900 * blockIdx.z;
    const int id2  = (wgid & 7) * 450 + (wgid >> 3);
    const int half = id2 & 1;
    int sp = id2 >> 1;
    const int w1i = sp % S; sp /= S;
    const int h1  = sp % S;
    const int b   = sp / S;
    const int tid = threadIdx.x;
    const int lane = tid & 63, wv = tid >> 6;
    const int m = lane & 31, hl = lane >> 5;
    const int rbase = half * 15 + wv * 4;

    uint4 F[6];
    l0_frags(x, b, h1, w1i, rbase, m, hl, F);

    f32x16 acc[4];
    // ---- branch 0 ----
    {
        uint4 Bs[3];
#pragma unroll
        for (int ss = 0; ss < 3; ++ss) Bs[ss] = bt[ss * 64 + lane];
#pragma unroll
        for (int r = 0; r < 4; ++r)
#pragma unroll
            for (int e = 0; e < 16; ++e) acc[r][e] = 0.f;
#pragma unroll
        for (int ss = 0; ss < 3; ++ss)
#pragma unroll
            for (int r = 0; r < 4; ++r)
                acc[r] = __builtin_amdgcn_mfma_f32_32x32x16_bf16(
                    __builtin_bit_cast(bf16x8, F[r + ss]),
                    __builtin_bit_cast(bf16x8, Bs[ss]), acc[r], 0, 0, 0);
        plane_epilogue(E[wv], acc, bias, y1a, b, h1, w1i, rbase, m, hl, lane, wv);
    }
    // ---- branch 1 ----
    {
        uint4 Bs[3];
#pragma unroll
        for (int ss = 0; ss < 3; ++ss) Bs[ss] = bt[192 + ss * 64 + lane];
#pragma unroll
        for (int r = 0; r < 4; ++r)
#pragma unroll
            for (int e = 0; e < 16; ++e) acc[r][e] = 0.f;
#pragma unroll
        for (int ss = 0; ss < 3; ++ss)
#pragma unroll
            for (int r = 0; r < 4; ++r)
                acc[r] = __builtin_amdgcn_mfma_f32_32x32x16_bf16(
                    __builtin_bit_cast(bf16x8, F[r + ss]),
                    __builtin_bit_cast(bf16x8, Bs[ss]), acc[r], 0, 0, 0);
        plane_epilogue(E[wv], acc, bias, y1b, b, h1, w1i, rbase, m, hl, lane, wv);
    }
}

// ---------------------------------------------------------------------------
// Layers 1/2 (R17, byte-identical): fallback path.
template<int LAYER, bool ACCUM>
__global__ __launch_bounds__(256, 2) void conv_k(
    const void* __restrict__ inp, const u32* __restrict__ ftab,
    const float* __restrict__ bias, void* __restrict__ outp)
{
    __shared__ float E[4][1056];
    __shared__ uint4 BT[1728];

    const int tid = threadIdx.x;
    {
        const uint4* g = (const uint4*)ftab;
#pragma unroll
        for (int j = 0; j < 7; ++j) {
            const int idx = j * 256 + tid;
            if (idx < 1728) BT[idx] = g[idx];
        }
    }
    __syncthreads();

    const int wgid = blockIdx.x + S * blockIdx.y + 900 * blockIdx.z;
    const int id2  = (wgid & 7) * 450 + (wgid >> 3);
    const int half = id2 & 1;
    int sp = id2 >> 1;
    const int w1i = sp % S; sp /= S;
    const int h1  = sp % S;
    const int b   = sp / S;

    const int lane = tid & 63, wv = tid >> 6;
    const int m = lane & 31, hl = lane >> 5;
    const int rbase = half * 15 + wv * 4;

    int rofs[6];
#pragma unroll
    for (int f = 0; f < 6; ++f) {
        int rr = rbase + f; if (rr > 31) rr = 31;
        rofs[f] = rr * 1024;
    }

    int kl[9], nk = 0;
#pragma unroll
    for (int k12 = 0; k12 < 9; ++k12) {
        const int g1 = h1 + k12 / 3 - 1, g2 = w1i + k12 % 3 - 1;
        if (g1 >= 0 && g1 < S && g2 >= 0 && g2 < S)
            kl[nk++] = (g1 * S + g2) | (k12 << 10);
    }

    f32x16 acc[4];
#pragma unroll
    for (int r = 0; r < 4; ++r)
#pragma unroll
        for (int e = 0; e < 16; ++e) acc[r][e] = 0.f;

    auto loadA = [&](uint4* Fd, int g) {
        const char* P = (const char*)inp + ((size_t)b * 900 + g) * PLANE
                        + m * 32 + hl * 16;
#pragma unroll
        for (int f = 0; f < 6; ++f)
            Fd[f] = *(const uint4*)(P + rofs[f]);
    };

    uint4 B0[3];
    {
        const int k0 = kl[0] >> 10;
#pragma unroll
        for (int f = 0; f < 3; ++f) B0[f] = BT[(k0 * 3 + f) * 64 + lane];
    }
    uint4 F[6];
    loadA(F, kl[0] & 1023);

    for (int ki = 0; ki + 1 < nk; ++ki) {
        const int gn = kl[ki + 1] & 1023, kn = kl[ki + 1] >> 10;
        uint4 FN[6];
        loadA(FN, gn);
        uint4 BN[3];
#pragma unroll
        for (int f = 0; f < 3; ++f) BN[f] = BT[(kn * 3 + f) * 64 + lane];

#pragma unroll
        for (int ss = 0; ss < 3; ++ss)
#pragma unroll
            for (int r = 0; r < 4; ++r)
                acc[r] = __builtin_amdgcn_mfma_f32_32x32x16_bf16(
                    __builtin_bit_cast(bf16x8, F[r + ss]),
                    __builtin_bit_cast(bf16x8, B0[ss]), acc[r], 0, 0, 0);

#pragma unroll
        for (int f = 0; f < 6; ++f) F[f] = FN[f];
#pragma unroll
        for (int f = 0; f < 3; ++f) B0[f] = BN[f];
    }
#pragma unroll
    for (int ss = 0; ss < 3; ++ss)
#pragma unroll
        for (int r = 0; r < 4; ++r)
            acc[r] = __builtin_amdgcn_mfma_f32_32x32x16_bf16(
                __builtin_bit_cast(bf16x8, F[r + ss]),
                __builtin_bit_cast(bf16x8, B0[ss]), acc[r], 0, 0, 0);

    float* Ew = E[wv];
    for (int r = 0; r < 4; ++r) {
        if (wv == 3 && r == 3) continue;
#pragma unroll
        for (int gq = 0; gq < 4; ++gq)
#pragma unroll
            for (int r4 = 0; r4 < 4; ++r4)
                Ew[m * 33 + 4 * hl + 8 * gq + r4] = acc[r][gq * 4 + r4];

        const int h2 = rbase + r;
        if (LAYER <= 1) {
            char* pl = (char*)outp + ((size_t)b * 900 + h1 * S + w1i) * PLANE
                       + (size_t)(h2 + 1) * 1024;
            const int t = lane >> 1, h8 = lane & 1;
            if (t < 30) {
                u32 wo[4];
#pragma unroll
                for (int p = 0; p < 4; ++p) {
                    const int c0 = 8 * h8 + 2 * p, c1 = c0 + 1;
                    float v0 = 0.f, v1 = 0.f;
                    if (c0 < 10)
                        v0 = fmaxf(Ew[c0 * 33 + t] + Ew[(10 + c0) * 33 + t + 1]
                                 + Ew[(20 + c0) * 33 + t + 2] + bias[c0], 0.f);
                    if (c1 < 10)
                        v1 = fmaxf(Ew[c1 * 33 + t] + Ew[(10 + c1) * 33 + t + 1]
                                 + Ew[(20 + c1) * 33 + t + 2] + bias[c1], 0.f);
                    wo[p] = (u32)f2bf(v0) | ((u32)f2bf(v1) << 16);
                }
                *(uint4*)(pl + (t + 1) * 32 + h8 * 16) =
                    make_uint4(wo[0], wo[1], wo[2], wo[3]);
            }
        } else {
            if (lane < 30) {
                const int t = lane;
                float v = Ew[t] + Ew[330 + t + 1] + Ew[660 + t + 2] + bias[0];
                v = fmaxf(v, 0.f);
                float* o = (float*)outp + (size_t)b * S4
                           + (size_t)(h1 * S + w1i) * 900 + h2 * 30 + t;
                if (ACCUM) *o += v; else *o = v;
            }
        }
    }
}

// ---------------------------------------------------------------------------
// Layer 1, BOTH branches in one z=8 dispatch: branch = z>>2 (wave-uniform),
// zq = z&3. Body identical to conv_k<1>; each block touches only its own
// branch's buffers (no L2 window doubling); z-order separates branches
// temporally; 3600%8==0 keeps per-branch XCD swizzle alignment.
__global__ __launch_bounds__(256, 2) void conv1ab_k(
    const void* __restrict__ y1a, const void* __restrict__ y1b,
    const u32* __restrict__ fta, const u32* __restrict__ ftb,
    const float* __restrict__ bias, void* __restrict__ y2a,
    void* __restrict__ y2b)
{
    __shared__ float E[4][1056];
    __shared__ uint4 BT[1728];

    const int br = blockIdx.z >> 2;
    const int zq = blockIdx.z & 3;
    const void* inp = br ? y1b : y1a;
    const u32* ftab = br ? ftb : fta;
    void* outp = br ? y2b : y2a;

    const int tid = threadIdx.x;
    {
        const uint4* g = (const uint4*)ftab;
#pragma unroll
        for (int j = 0; j < 7; ++j) {
            const int idx = j * 256 + tid;
            if (idx < 1728) BT[idx] = g[idx];
        }
    }
    __syncthreads();

    const int wgid = blockIdx.x + S * blockIdx.y + 900 * zq;
    const int id2  = (wgid & 7) * 450 + (wgid >> 3);
    const int half = id2 & 1;
    int sp = id2 >> 1;
    const int w1i = sp % S; sp /= S;
    const int h1  = sp % S;
    const int b   = sp / S;

    const int lane = tid & 63, wv = tid >> 6;
    const int m = lane & 31, hl = lane >> 5;
    const int rbase = half * 15 + wv * 4;

    int rofs[6];
#pragma unroll
    for (int f = 0; f < 6; ++f) {
        int rr = rbase + f; if (rr > 31) rr = 31;
        rofs[f] = rr * 1024;
    }

    int kl[9], nk = 0;
#pragma unroll
    for (int k12 = 0; k12 < 9; ++k12) {
        const int g1 = h1 + k12 / 3 - 1, g2 = w1i + k12 % 3 - 1;
        if (g1 >= 0 && g1 < S && g2 >= 0 && g2 < S)
            kl[nk++] = (g1 * S + g2) | (k12 << 10);
    }

    f32x16 acc[4];
#pragma unroll
    for (int r = 0; r < 4; ++r)
#pragma unroll
        for (int e = 0; e < 16; ++e) acc[r][e] = 0.f;

    auto loadA = [&](uint4* Fd, int g) {
        const char* P = (const char*)inp + ((size_t)b * 900 + g) * PLANE
                        + m * 32 + hl * 16;
#pragma unroll
        for (int f = 0; f < 6; ++f)
            Fd[f] = *(const uint4*)(P + rofs[f]);
    };

    uint4 B0[3];
    {
        const int k0 = kl[0] >> 10;
#pragma unroll
        for (int f = 0; f < 3; ++f) B0[f] = BT[(k0 * 3 + f) * 64 + lane];
    }
    uint4 F[6];
    loadA(F, kl[0] & 1023);

    for (int ki = 0; ki + 1 < nk; ++ki) {
        const int gn = kl[ki + 1] & 1023, kn = kl[ki + 1] >> 10;
        uint4 FN[6];
        loadA(FN, gn);
        uint4 BN[3];
#pragma unroll
        for (int f = 0; f < 3; ++f) BN[f] = BT[(kn * 3 + f) * 64 + lane];

#pragma unroll
        for (int ss = 0; ss < 3; ++ss)
#pragma unroll
            for (int r = 0; r < 4; ++r)
                acc[r] = __builtin_amdgcn_mfma_f32_32x32x16_bf16(
                    __builtin_bit_cast(bf16x8, F[r + ss]),
                    __builtin_bit_cast(bf16x8, B0[ss]), acc[r], 0, 0, 0);

#pragma unroll
        for (int f = 0; f < 6; ++f) F[f] = FN[f];
#pragma unroll
        for (int f = 0; f < 3; ++f) B0[f] = BN[f];
    }
#pragma unroll
    for (int ss = 0; ss < 3; ++ss)
#pragma unroll
        for (int r = 0; r < 4; ++r)
            acc[r] = __builtin_amdgcn_mfma_f32_32x32x16_bf16(
                __builtin_bit_cast(bf16x8, F[r + ss]),
                __builtin_bit_cast(bf16x8, B0[ss]), acc[r], 0, 0, 0);

    plane_epilogue(E[wv], acc, bias, outp, b, h1, w1i, rbase, m, hl, lane, wv);
}

// ---------------------------------------------------------------------------
// Layer 2, BOTH branches (merged path): taps over y2a then y2b; epilogue-a
// stashed in registers; single out store (no RMW). LDS: both B-tables;
// E overlays dead BTS[0] behind a barrier after taps-a.
__global__ __launch_bounds__(256, 2) void conv2ab_k(
    const void* __restrict__ y2a, const void* __restrict__ y2b,
    const u32* __restrict__ fta, const u32* __restrict__ ftb,
    const float* __restrict__ bias, float* __restrict__ out)
{
    __shared__ uint4 BTS[2][1728];        // branch tables; E overlays BTS[0]

    const int tid = threadIdx.x;
    {
        const uint4* ga = (const uint4*)fta;
        const uint4* gb = (const uint4*)ftb;
#pragma unroll
        for (int j = 0; j < 7; ++j) {
            const int idx = j * 256 + tid;
            if (idx < 1728) { BTS[0][idx] = ga[idx]; BTS[1][idx] = gb[idx]; }
        }
    }
    __syncthreads();

    const int wgid = blockIdx.x + S * blockIdx.y + 900 * blockIdx.z;
    const int id2  = (wgid & 7) * 450 + (wgid >> 3);
    const int half = id2 & 1;
    int sp = id2 >> 1;
    const int w1i = sp % S; sp /= S;
    const int h1  = sp % S;
    const int b   = sp / S;

    const int lane = tid & 63, wv = tid >> 6;
    const int m = lane & 31, hl = lane >> 5;
    const int rbase = half * 15 + wv * 4;

    int rofs[6];
#pragma unroll
    for (int f = 0; f < 6; ++f) {
        int rr = rbase + f; if (rr > 31) rr = 31;
        rofs[f] = rr * 1024;
    }

    int kl[9], nk = 0;
#pragma unroll
    for (int k12 = 0; k12 < 9; ++k12) {
        const int g1 = h1 + k12 / 3 - 1, g2 = w1i + k12 % 3 - 1;
        if (g1 >= 0 && g1 < S && g2 >= 0 && g2 < S)
            kl[nk++] = (g1 * S + g2) | (k12 << 10);
    }

    f32x16 acc[4];

    auto run_taps = [&](const void* inp, const uint4* BTb) {
#pragma unroll
        for (int r = 0; r < 4; ++r)
#pragma unroll
            for (int e = 0; e < 16; ++e) acc[r][e] = 0.f;
        auto loadA = [&](uint4* Fd, int g) {
            const char* P = (const char*)inp + ((size_t)b * 900 + g) * PLANE
                            + m * 32 + hl * 16;
#pragma unroll
            for (int f = 0; f < 6; ++f)
                Fd[f] = *(const uint4*)(P + rofs[f]);
        };
        uint4 B0[3];
        {
            const int k0 = kl[0] >> 10;
#pragma unroll
            for (int f = 0; f < 3; ++f) B0[f] = BTb[(k0 * 3 + f) * 64 + lane];
        }
        uint4 F[6];
        loadA(F, kl[0] & 1023);
        for (int ki = 0; ki + 1 < nk; ++ki) {
            const int gn = kl[ki + 1] & 1023, kn = kl[ki + 1] >> 10;
            uint4 FN[6];
            loadA(FN, gn);
            uint4 BN[3];
#pragma unroll
            for (int f = 0; f < 3; ++f) BN[f] = BTb[(kn * 3 + f) * 64 + lane];
#pragma unroll
            for (int ss = 0; ss < 3; ++ss)
#pragma unroll
                for (int r = 0; r < 4; ++r)
                    acc[r] = __builtin_amdgcn_mfma_f32_32x32x16_bf16(
                        __builtin_bit_cast(bf16x8, F[r + ss]),
                        __builtin_bit_cast(bf16x8, B0[ss]), acc[r], 0, 0, 0);
#pragma unroll
            for (int f = 0; f < 6; ++f) F[f] = FN[f];
#pragma unroll
            for (int f = 0; f < 3; ++f) B0[f] = BN[f];
        }
#pragma unroll
        for (int ss = 0; ss < 3; ++ss)
#pragma unroll
            for (int r = 0; r < 4; ++r)
                acc[r] = __builtin_amdgcn_mfma_f32_32x32x16_bf16(
                    __builtin_bit_cast(bf16x8, F[r + ss]),
                    __builtin_bit_cast(bf16x8, B0[ss]), acc[r], 0, 0, 0);
    };

    // ---- branch 0 taps ----
    run_taps(y2a, BTS[0]);
    __syncthreads();                      // all waves done with BTS[0]
    float* Ew = (float*)&BTS[0][0] + wv * 1056;   // E overlays dead BTS[0]

    float va[4] = {0.f, 0.f, 0.f, 0.f};
    for (int r = 0; r < 4; ++r) {
        if (wv == 3 && r == 3) continue;
#pragma unroll
        for (int gq = 0; gq < 4; ++gq)
#pragma unroll
            for (int r4 = 0; r4 < 4; ++r4)
                Ew[m * 33 + 4 * hl + 8 * gq + r4] = acc[r][gq * 4 + r4];
        if (lane < 30) {
            const int t = lane;
            va[r] = fmaxf(Ew[t] + Ew[330 + t + 1] + Ew[660 + t + 2] + bias[0], 0.f);
        }
    }

    // ---- branch 1 taps (BTS[1] untouched by E overlay) ----
    run_taps(y2b, BTS[1]);
    for (int r = 0; r < 4; ++r) {
        if (wv == 3 && r == 3) continue;
#pragma unroll
        for (int gq = 0; gq < 4; ++gq)
#pragma unroll
            for (int r4 = 0; r4 < 4; ++r4)
                Ew[m * 33 + 4 * hl + 8 * gq + r4] = acc[r][gq * 4 + r4];
        const int h2 = rbase + r;
        if (lane < 30) {
            const int t = lane;
            float v = fmaxf(Ew[t] + Ew[330 + t + 1] + Ew[660 + t + 2] + bias[0], 0.f);
            out[(size_t)b * S4 + (size_t)(h1 * S + w1i) * 900 + h2 * 30 + t]
                = va[r] + v;
        }
    }
}

// ---------------------------------------------------------------------------
extern "C" void kernel_launch(void* const* d_in, const int* in_sizes, int n_in,
                              void* d_out, int out_size, void* d_ws, size_t ws_size,
                              hipStream_t stream)
{
    const float* x   = (const float*)d_in[0];
    const float* w1p = (const float*)d_in[1];
    const float* b1p = (const float*)d_in[2];
    const float* w2p = (const float*)d_in[3];
    const float* b2p = (const float*)d_in[4];
    const float* w3p = (const float*)d_in[5];
    const float* b3p = (const float*)d_in[6];
    float* out = (float*)d_out;

    u32* ft = (u32*)d_ws;
    const uint4* ftL0 = (const uint4*)d_ws + 6 * 27 * 64;
    u16* y1a = (u16*)((char*)d_ws + 172032);
    u16* y1b = (u16*)((char*)y1a + YBYTES);
    u16* y2a = (u16*)((char*)y1b + YBYTES);

    const u32* f2b0 = ft + (size_t)2 * 27 * 64 * 4;
    const u32* f2b1 = ft + (size_t)3 * 27 * 64 * 4;
    const u32* f3b0 = ft + (size_t)4 * 27 * 64 * 4;
    const u32* f3b1 = ft + (size_t)5 * 27 * 64 * 4;

    dim3 grid(S, S, 4), grid8(S, S, 8), blk(256);
    const size_t need = 172032 + 3 * YBYTES;

    if (ws_size >= need) {
        // Merged path: 4 dispatches. y2b aliases y1a (dead after L1a reads
        // complete -- L1a and L1b are in the SAME dispatch, but branch-b
        // blocks write y2b=y1a only after... NOTE: alias is NOT safe here;
        // use y1b as y2b instead: y1b is read by branch-b blocks in the
        // same dispatch. Neither alias is safe intra-dispatch -> y2b gets
        // its own region only if ws allows; else fall back.
        if (ws_size >= 172032 + 4 * YBYTES) {
            u16* y2b = (u16*)((char*)y2a + YBYTES);
            prep_k<<<1842, blk, 0, stream>>>(ft, w1p, w2p, w3p, y1a, y1b, y2a);
            // y2b halos: zero via second prep pass on y2b only (reuse p1=p2=p3=y2b)
            prep_k<<<1842, blk, 0, stream>>>(ft, w1p, w2p, w3p, y2b, y2b, y2b);
            conv0ab_k<<<grid, blk, 0, stream>>>(x, ftL0, b1p, (void*)y1a, (void*)y1b);
            conv1ab_k<<<grid8, blk, 0, stream>>>(y1a, y1b, f2b0, f2b1, b2p,
                                                 (void*)y2a, (void*)y2b);
            conv2ab_k<<<grid, blk, 0, stream>>>(y2a, y2b, f3b0, f3b1, b3p, out);
        } else {
            // R23 merged path (5 dispatches), alias y2b = y1a (safe: separate
            // dispatches order L1a before L1b).
            u16* y2b = y1a;
            prep_k<<<1842, blk, 0, stream>>>(ft, w1p, w2p, w3p, y1a, y1b, y2a);
            conv0ab_k<<<grid, blk, 0, stream>>>(x, ftL0, b1p, (void*)y1a, (void*)y1b);
            conv_k<1, false><<<grid, blk, 0, stream>>>(y1a, f2b0, b2p, (void*)y2a);
            conv_k<1, false><<<grid, blk, 0, stream>>>(y1b, f2b1, b2p, (void*)y2b);
            conv2ab_k<<<grid, blk, 0, stream>>>(y2a, y2b, f3b0, f3b1, b3p, out);
        }
    } else {
        // Fallback: exact R22 path (2 buffers: y1a, y1b-as-y2).
        u16* y1 = y1a;
        u16* y2 = y1b;
        prep_k<<<1842, blk, 0, stream>>>(ft, w1p, w2p, w3p, y1, y2, y2);
        for (int br = 0; br < 2; ++br) {
            const u32* f2 = (br == 0) ? f2b0 : f2b1;
            const u32* f3 = (br == 0) ? f3b0 : f3b1;
            conv0_k<<<grid, blk, 0, stream>>>(x, ftL0 + br * 192, b1p, (void*)y1);
            conv_k<1, false><<<grid, blk, 0, stream>>>(y1, f2, b2p, (void*)y2);
            if (br == 0)
                conv_k<2, false><<<grid, blk, 0, stream>>>(y2, f3, b3p, (void*)out);
            else
                conv_k<2, true><<<grid, blk, 0, stream>>>(y2, f3, b3p, (void*)out);
        }
    }
}

// Round 18
// 365.242 us; speedup vs baseline: 1.2538x; 1.0242x over previous
//
#include <hip/hip_runtime.h>

// 4D conv net, MI355X. S=30, B=2, ch 1->10->10->1, kernel 3^4, pad 1, ReLU.
// out = net(x,w) + net(x,w_swap), w_swap has (k1,k2)<->(k3,k4).
// R7-R17: 32x32x16 bf16 MFMA, XCD-chunk swizzle, B-table in LDS, rotate-A
// depth-1 prefetch, barrier-free per-wave epilogue. conv_k = 69.5 us.
// R22: R17 kernels + fused prep (384 us).
// R23 (375 us): branch-endpoint merges conv0ab/conv2ab (single out store,
// WRITE 81->6.3 MB; conv2ab FETCH 160 MB dual-buffer thrash but net win).
// R24 (374 us): conv1ab merges both L1 dispatches (z=8, branch=z>>2);
// landed 127 us as predicted (no thrash, per-branch signatures), but the
// gain was spent on a SECOND prep dispatch zeroing y2b.
// R25: prep_k zero-role takes all FOUR buffers in one pass; second prep
// dispatch dropped. 5 dispatches total. Everything else byte-identical.

static constexpr int S  = 30;
static constexpr long S4 = 810000;
static constexpr size_t PLANE = 32768;                  // 32*32*16*2 B
static constexpr size_t YBYTES = (size_t)1800 * PLANE;  // [b(2)][g1][g2]

typedef __bf16 bf16x8 __attribute__((ext_vector_type(8)));
typedef float  f32x16 __attribute__((ext_vector_type(16)));
typedef unsigned int  u32;
typedef unsigned short u16;

static __device__ __forceinline__ u16 f2bf(float f) {
    u32 u = __builtin_bit_cast(u32, f);
    return (u16)((u + 0x7fffu + ((u >> 16) & 1u)) >> 16);
}

// ---------------------------------------------------------------------------
// Fused prep: blocks 0..41 build the B-fragment tables (42*256 = 10752 ids
// exactly); blocks 42..1841 zero halo positions of up to 4 y-buffers.
// Main table: [set(6)][k12(9)][k3(3)][lane(64)] uint4 (sets 0/1 unused).
// L0-packed (appended): [branch(2)][k3(3)][lane(64)] uint4.
__global__ __launch_bounds__(256) void prep_k(u32* __restrict__ ft,
    const float* __restrict__ w1, const float* __restrict__ w2,
    const float* __restrict__ w3, u16* __restrict__ p1,
    u16* __restrict__ p2, u16* __restrict__ p3, u16* __restrict__ p4)
{
    const int tid = threadIdx.x;
    if (blockIdx.x >= 42) {                    // ---- zero role ----
        const int pb = blockIdx.x - 42;
        if (tid >= 124) return;
        int hp, tp;
        if (tid < 32)      { hp = 0;        tp = tid; }
        else if (tid < 64) { hp = 31;       tp = tid - 32; }
        else if (tid < 94) { hp = tid - 63; tp = 0; }
        else               { hp = tid - 93; tp = 31; }
        const size_t off = (size_t)pb * PLANE + hp * 1024 + tp * 32;
        const uint4 z = make_uint4(0, 0, 0, 0);
        *(uint4*)((char*)p1 + off)      = z;
        *(uint4*)((char*)p1 + off + 16) = z;
        *(uint4*)((char*)p2 + off)      = z;
        *(uint4*)((char*)p2 + off + 16) = z;
        *(uint4*)((char*)p3 + off)      = z;
        *(uint4*)((char*)p3 + off + 16) = z;
        *(uint4*)((char*)p4 + off)      = z;
        *(uint4*)((char*)p4 + off + 16) = z;
        return;
    }
    // ---- fragprep role ----
    const int gid = blockIdx.x * 256 + tid;    // 0..10751
    const int lane = gid & 63;
    const int n = lane & 31, hl = lane >> 5;
    u16 us[8];
#pragma unroll
    for (int j = 0; j < 8; ++j) us[j] = 0;

    if (gid < 6 * 27 * 64) {
        int r = gid >> 6;
        const int k3 = r % 3; r /= 3;
        const int k12 = r % 9; const int set = r / 9;
        const int layer = set >> 1, swap = set & 1;
        const int k1 = k12 / 3, k2 = k12 % 3;
        if (n < 30) {
            const int k4 = (n < 10) ? 0 : ((n < 20) ? 1 : 2);
            const int co = n - 10 * k4;
            const int i1 = swap ? k3 : k1, i2 = swap ? k4 : k2;
            const int i3 = swap ? k1 : k3, i4 = swap ? k2 : k4;
            const int widx = ((i1 * 3 + i2) * 3 + i3) * 3 + i4;
#pragma unroll
            for (int j = 0; j < 8; ++j) {
                const int k = hl * 8 + j;
                float wv = 0.f;
                if (layer == 0) { if (k == 0) wv = w1[co * 81 + widx]; }
                else if (layer == 1) { if (k < 10) wv = w2[(co * 10 + k) * 81 + widx]; }
                else { if (k < 10 && co == 0) wv = w3[k * 81 + widx]; }
                us[j] = f2bf(wv);
            }
        }
    } else {
        const int idx = gid - 6 * 27 * 64;       // 0..383
        int r = idx >> 6;                        // 0..5
        const int k3 = r % 3, swap = r / 3;
        if (n < 30) {
            const int k4 = (n < 10) ? 0 : ((n < 20) ? 1 : 2);
            const int co = n - 10 * k4;
#pragma unroll
            for (int j = 0; j < 8; ++j) {
                const int k12 = hl * 8 + j;
                if (k12 < 9) {
                    const int k1 = k12 / 3, k2 = k12 % 3;
                    const int i1 = swap ? k3 : k1, i2 = swap ? k4 : k2;
                    const int i3 = swap ? k1 : k3, i4 = swap ? k2 : k4;
                    const int widx = ((i1 * 3 + i2) * 3 + i3) * 3 + i4;
                    us[j] = f2bf(w1[co * 81 + widx]);
                }
            }
        }
    }
    u32* o = ft + (size_t)gid * 4;
    o[0] = (u32)us[0] | ((u32)us[1] << 16);
    o[1] = (u32)us[2] | ((u32)us[3] << 16);
    o[2] = (u32)us[4] | ((u32)us[5] << 16);
    o[3] = (u32)us[6] | ((u32)us[7] << 16);
}

// ---------------------------------------------------------------------------
// Common L0 A-fragment build + epilogue as device helpers.
static __device__ __forceinline__ void l0_frags(
    const float* __restrict__ x, int b, int h1, int w1i, int rbase,
    int m, int hl, uint4* F)
{
    int gof[9]; int gokm = 0;
#pragma unroll
    for (int k12 = 0; k12 < 9; ++k12) {
        const int g1 = h1 + k12 / 3 - 1, g2 = w1i + k12 % 3 - 1;
        gof[k12] = 0;
        if (g1 >= 0 && g1 < S && g2 >= 0 && g2 < S) {
            gof[k12] = (g1 * S + g2) * 900; gokm |= 1 << k12;
        }
    }
    const float* xb = x + (size_t)b * S4;
#pragma unroll
    for (int f = 0; f < 6; ++f) {
        const int hp = rbase + f;
        const bool rk = (hp >= 1 && hp <= 30 && m >= 1 && m <= 30);
        const int ro = (hp - 1) * 30 + (m - 1);
        u16 av[8];
#pragma unroll
        for (int j = 0; j < 8; ++j) av[j] = 0;
        if (hl == 0) {
#pragma unroll
            for (int j = 0; j < 8; ++j) {
                float v = 0.f;
                if (rk && ((gokm >> j) & 1)) v = xb[gof[j] + ro];
                av[j] = f2bf(v);
            }
        } else {
            float v = 0.f;
            if (rk && ((gokm >> 8) & 1)) v = xb[gof[8] + ro];
            av[0] = f2bf(v);
        }
        F[f] = make_uint4((u32)av[0] | ((u32)av[1] << 16),
                          (u32)av[2] | ((u32)av[3] << 16),
                          (u32)av[4] | ((u32)av[5] << 16),
                          (u32)av[6] | ((u32)av[7] << 16));
    }
}

static __device__ __forceinline__ void plane_epilogue(
    float* Ew, const f32x16* acc, const float* __restrict__ bias,
    void* __restrict__ outp, int b, int h1, int w1i, int rbase,
    int m, int hl, int lane, int wv)
{
    for (int r = 0; r < 4; ++r) {
        if (wv == 3 && r == 3) continue;
#pragma unroll
        for (int gq = 0; gq < 4; ++gq)
#pragma unroll
            for (int r4 = 0; r4 < 4; ++r4)
                Ew[m * 33 + 4 * hl + 8 * gq + r4] = acc[r][gq * 4 + r4];

        const int h2 = rbase + r;
        char* pl = (char*)outp + ((size_t)b * 900 + h1 * S + w1i) * PLANE
                   + (size_t)(h2 + 1) * 1024;
        const int t = lane >> 1, h8 = lane & 1;
        if (t < 30) {
            u32 wo[4];
#pragma unroll
            for (int p = 0; p < 4; ++p) {
                const int c0 = 8 * h8 + 2 * p, c1 = c0 + 1;
                float v0 = 0.f, v1 = 0.f;
                if (c0 < 10)
                    v0 = fmaxf(Ew[c0 * 33 + t] + Ew[(10 + c0) * 33 + t + 1]
                             + Ew[(20 + c0) * 33 + t + 2] + bias[c0], 0.f);
                if (c1 < 10)
                    v1 = fmaxf(Ew[c1 * 33 + t] + Ew[(10 + c1) * 33 + t + 1]
                             + Ew[(20 + c1) * 33 + t + 2] + bias[c1], 0.f);
                wo[p] = (u32)f2bf(v0) | ((u32)f2bf(v1) << 16);
            }
            *(uint4*)(pl + (t + 1) * 32 + h8 * 16) =
                make_uint4(wo[0], wo[1], wo[2], wo[3]);
        }
    }
}

// ---------------------------------------------------------------------------
// Layer 0, single branch (R13, fallback path).
__global__ __launch_bounds__(256, 4) void conv0_k(
    const float* __restrict__ x, const uint4* __restrict__ bt,
    const float* __restrict__ bias, void* __restrict__ outp)
{
    __shared__ float E[4][1056];
    const int wgid = blockIdx.x + S * blockIdx.y + 900 * blockIdx.z;
    const int id2  = (wgid & 7) * 450 + (wgid >> 3);
    const int half = id2 & 1;
    int sp = id2 >> 1;
    const int w1i = sp % S; sp /= S;
    const int h1  = sp % S;
    const int b   = sp / S;
    const int tid = threadIdx.x;
    const int lane = tid & 63, wv = tid >> 6;
    const int m = lane & 31, hl = lane >> 5;
    const int rbase = half * 15 + wv * 4;

    uint4 Bs[3];
#pragma unroll
    for (int ss = 0; ss < 3; ++ss) Bs[ss] = bt[ss * 64 + lane];

    uint4 F[6];
    l0_frags(x, b, h1, w1i, rbase, m, hl, F);

    f32x16 acc[4];
#pragma unroll
    for (int r = 0; r < 4; ++r)
#pragma unroll
        for (int e = 0; e < 16; ++e) acc[r][e] = 0.f;
#pragma unroll
    for (int ss = 0; ss < 3; ++ss)
#pragma unroll
        for (int r = 0; r < 4; ++r)
            acc[r] = __builtin_amdgcn_mfma_f32_32x32x16_bf16(
                __builtin_bit_cast(bf16x8, F[r + ss]),
                __builtin_bit_cast(bf16x8, Bs[ss]), acc[r], 0, 0, 0);

    plane_epilogue(E[wv], acc, bias, outp, b, h1, w1i, rbase, m, hl, lane, wv);
}

// ---------------------------------------------------------------------------
// Layer 0, BOTH branches (merged path): x-fragments loaded once, two MFMA
// sets, two epilogues (y1a, y1b).
__global__ __launch_bounds__(256, 2) void conv0ab_k(
    const float* __restrict__ x, const uint4* __restrict__ bt,
    const float* __restrict__ bias, void* __restrict__ y1a,
    void* __restrict__ y1b)
{
    __shared__ float E[4][1056];
    const int wgid = blockIdx.x + S * blockIdx.y + 900 * blockIdx.z;
    const int id2  = (wgid & 7) * 450 + (wgid >> 3);
    const int half = id2 & 1;
    int sp = id2 >> 1;
    const int w1i = sp % S; sp /= S;
    const int h1  = sp % S;
    const int b   = sp / S;
    const int tid = threadIdx.x;
    const int lane = tid & 63, wv = tid >> 6;
    const int m = lane & 31, hl = lane >> 5;
    const int rbase = half * 15 + wv * 4;

    uint4 F[6];
    l0_frags(x, b, h1, w1i, rbase, m, hl, F);

    f32x16 acc[4];
    // ---- branch 0 ----
    {
        uint4 Bs[3];
#pragma unroll
        for (int ss = 0; ss < 3; ++ss) Bs[ss] = bt[ss * 64 + lane];
#pragma unroll
        for (int r = 0; r < 4; ++r)
#pragma unroll
            for (int e = 0; e < 16; ++e) acc[r][e] = 0.f;
#pragma unroll
        for (int ss = 0; ss < 3; ++ss)
#pragma unroll
            for (int r = 0; r < 4; ++r)
                acc[r] = __builtin_amdgcn_mfma_f32_32x32x16_bf16(
                    __builtin_bit_cast(bf16x8, F[r + ss]),
                    __builtin_bit_cast(bf16x8, Bs[ss]), acc[r], 0, 0, 0);
        plane_epilogue(E[wv], acc, bias, y1a, b, h1, w1i, rbase, m, hl, lane, wv);
    }
    // ---- branch 1 ----
    {
        uint4 Bs[3];
#pragma unroll
        for (int ss = 0; ss < 3; ++ss) Bs[ss] = bt[192 + ss * 64 + lane];
#pragma unroll
        for (int r = 0; r < 4; ++r)
#pragma unroll
            for (int e = 0; e < 16; ++e) acc[r][e] = 0.f;
#pragma unroll
        for (int ss = 0; ss < 3; ++ss)
#pragma unroll
            for (int r = 0; r < 4; ++r)
                acc[r] = __builtin_amdgcn_mfma_f32_32x32x16_bf16(
                    __builtin_bit_cast(bf16x8, F[r + ss]),
                    __builtin_bit_cast(bf16x8, Bs[ss]), acc[r], 0, 0, 0);
        plane_epilogue(E[wv], acc, bias, y1b, b, h1, w1i, rbase, m, hl, lane, wv);
    }
}

// ---------------------------------------------------------------------------
// Layers 1/2 (R17, byte-identical): fallback path.
template<int LAYER, bool ACCUM>
__global__ __launch_bounds__(256, 2) void conv_k(
    const void* __restrict__ inp, const u32* __restrict__ ftab,
    const float* __restrict__ bias, void* __restrict__ outp)
{
    __shared__ float E[4][1056];
    __shared__ uint4 BT[1728];

    const int tid = threadIdx.x;
    {
        const uint4* g = (const uint4*)ftab;
#pragma unroll
        for (int j = 0; j < 7; ++j) {
            const int idx = j * 256 + tid;
            if (idx < 1728) BT[idx] = g[idx];
        }
    }
    __syncthreads();

    const int wgid = blockIdx.x + S * blockIdx.y + 900 * blockIdx.z;
    const int id2  = (wgid & 7) * 450 + (wgid >> 3);
    const int half = id2 & 1;
    int sp = id2 >> 1;
    const int w1i = sp % S; sp /= S;
    const int h1  = sp % S;
    const int b   = sp / S;

    const int lane = tid & 63, wv = tid >> 6;
    const int m = lane & 31, hl = lane >> 5;
    const int rbase = half * 15 + wv * 4;

    int rofs[6];
#pragma unroll
    for (int f = 0; f < 6; ++f) {
        int rr = rbase + f; if (rr > 31) rr = 31;
        rofs[f] = rr * 1024;
    }

    int kl[9], nk = 0;
#pragma unroll
    for (int k12 = 0; k12 < 9; ++k12) {
        const int g1 = h1 + k12 / 3 - 1, g2 = w1i + k12 % 3 - 1;
        if (g1 >= 0 && g1 < S && g2 >= 0 && g2 < S)
            kl[nk++] = (g1 * S + g2) | (k12 << 10);
    }

    f32x16 acc[4];
#pragma unroll
    for (int r = 0; r < 4; ++r)
#pragma unroll
        for (int e = 0; e < 16; ++e) acc[r][e] = 0.f;

    auto loadA = [&](uint4* Fd, int g) {
        const char* P = (const char*)inp + ((size_t)b * 900 + g) * PLANE
                        + m * 32 + hl * 16;
#pragma unroll
        for (int f = 0; f < 6; ++f)
            Fd[f] = *(const uint4*)(P + rofs[f]);
    };

    uint4 B0[3];
    {
        const int k0 = kl[0] >> 10;
#pragma unroll
        for (int f = 0; f < 3; ++f) B0[f] = BT[(k0 * 3 + f) * 64 + lane];
    }
    uint4 F[6];
    loadA(F, kl[0] & 1023);

    for (int ki = 0; ki + 1 < nk; ++ki) {
        const int gn = kl[ki + 1] & 1023, kn = kl[ki + 1] >> 10;
        uint4 FN[6];
        loadA(FN, gn);
        uint4 BN[3];
#pragma unroll
        for (int f = 0; f < 3; ++f) BN[f] = BT[(kn * 3 + f) * 64 + lane];

#pragma unroll
        for (int ss = 0; ss < 3; ++ss)
#pragma unroll
            for (int r = 0; r < 4; ++r)
                acc[r] = __builtin_amdgcn_mfma_f32_32x32x16_bf16(
                    __builtin_bit_cast(bf16x8, F[r + ss]),
                    __builtin_bit_cast(bf16x8, B0[ss]), acc[r], 0, 0, 0);

#pragma unroll
        for (int f = 0; f < 6; ++f) F[f] = FN[f];
#pragma unroll
        for (int f = 0; f < 3; ++f) B0[f] = BN[f];
    }
#pragma unroll
    for (int ss = 0; ss < 3; ++ss)
#pragma unroll
        for (int r = 0; r < 4; ++r)
            acc[r] = __builtin_amdgcn_mfma_f32_32x32x16_bf16(
                __builtin_bit_cast(bf16x8, F[r + ss]),
                __builtin_bit_cast(bf16x8, B0[ss]), acc[r], 0, 0, 0);

    float* Ew = E[wv];
    for (int r = 0; r < 4; ++r) {
        if (wv == 3 && r == 3) continue;
#pragma unroll
        for (int gq = 0; gq < 4; ++gq)
#pragma unroll
            for (int r4 = 0; r4 < 4; ++r4)
                Ew[m * 33 + 4 * hl + 8 * gq + r4] = acc[r][gq * 4 + r4];

        const int h2 = rbase + r;
        if (LAYER <= 1) {
            char* pl = (char*)outp + ((size_t)b * 900 + h1 * S + w1i) * PLANE
                       + (size_t)(h2 + 1) * 1024;
            const int t = lane >> 1, h8 = lane & 1;
            if (t < 30) {
                u32 wo[4];
#pragma unroll
                for (int p = 0; p < 4; ++p) {
                    const int c0 = 8 * h8 + 2 * p, c1 = c0 + 1;
                    float v0 = 0.f, v1 = 0.f;
                    if (c0 < 10)
                        v0 = fmaxf(Ew[c0 * 33 + t] + Ew[(10 + c0) * 33 + t + 1]
                                 + Ew[(20 + c0) * 33 + t + 2] + bias[c0], 0.f);
                    if (c1 < 10)
                        v1 = fmaxf(Ew[c1 * 33 + t] + Ew[(10 + c1) * 33 + t + 1]
                                 + Ew[(20 + c1) * 33 + t + 2] + bias[c1], 0.f);
                    wo[p] = (u32)f2bf(v0) | ((u32)f2bf(v1) << 16);
                }
                *(uint4*)(pl + (t + 1) * 32 + h8 * 16) =
                    make_uint4(wo[0], wo[1], wo[2], wo[3]);
            }
        } else {
            if (lane < 30) {
                const int t = lane;
                float v = Ew[t] + Ew[330 + t + 1] + Ew[660 + t + 2] + bias[0];
                v = fmaxf(v, 0.f);
                float* o = (float*)outp + (size_t)b * S4
                           + (size_t)(h1 * S + w1i) * 900 + h2 * 30 + t;
                if (ACCUM) *o += v; else *o = v;
            }
        }
    }
}

// ---------------------------------------------------------------------------
// Layer 1, BOTH branches in one z=8 dispatch: branch = z>>2 (wave-uniform),
// zq = z&3. Body identical to conv_k<1>; each block touches only its own
// branch's buffers; z-order separates branches temporally in L2.
__global__ __launch_bounds__(256, 2) void conv1ab_k(
    const void* __restrict__ y1a, const void* __restrict__ y1b,
    const u32* __restrict__ fta, const u32* __restrict__ ftb,
    const float* __restrict__ bias, void* __restrict__ y2a,
    void* __restrict__ y2b)
{
    __shared__ float E[4][1056];
    __shared__ uint4 BT[1728];

    const int br = blockIdx.z >> 2;
    const int zq = blockIdx.z & 3;
    const void* inp = br ? y1b : y1a;
    const u32* ftab = br ? ftb : fta;
    void* outp = br ? y2b : y2a;

    const int tid = threadIdx.x;
    {
        const uint4* g = (const uint4*)ftab;
#pragma unroll
        for (int j = 0; j < 7; ++j) {
            const int idx = j * 256 + tid;
            if (idx < 1728) BT[idx] = g[idx];
        }
    }
    __syncthreads();

    const int wgid = blockIdx.x + S * blockIdx.y + 900 * zq;
    const int id2  = (wgid & 7) * 450 + (wgid >> 3);
    const int half = id2 & 1;
    int sp = id2 >> 1;
    const int w1i = sp % S; sp /= S;
    const int h1  = sp % S;
    const int b   = sp / S;

    const int lane = tid & 63, wv = tid >> 6;
    const int m = lane & 31, hl = lane >> 5;
    const int rbase = half * 15 + wv * 4;

    int rofs[6];
#pragma unroll
    for (int f = 0; f < 6; ++f) {
        int rr = rbase + f; if (rr > 31) rr = 31;
        rofs[f] = rr * 1024;
    }

    int kl[9], nk = 0;
#pragma unroll
    for (int k12 = 0; k12 < 9; ++k12) {
        const int g1 = h1 + k12 / 3 - 1, g2 = w1i + k12 % 3 - 1;
        if (g1 >= 0 && g1 < S && g2 >= 0 && g2 < S)
            kl[nk++] = (g1 * S + g2) | (k12 << 10);
    }

    f32x16 acc[4];
#pragma unroll
    for (int r = 0; r < 4; ++r)
#pragma unroll
        for (int e = 0; e < 16; ++e) acc[r][e] = 0.f;

    auto loadA = [&](uint4* Fd, int g) {
        const char* P = (const char*)inp + ((size_t)b * 900 + g) * PLANE
                        + m * 32 + hl * 16;
#pragma unroll
        for (int f = 0; f < 6; ++f)
            Fd[f] = *(const uint4*)(P + rofs[f]);
    };

    uint4 B0[3];
    {
        const int k0 = kl[0] >> 10;
#pragma unroll
        for (int f = 0; f < 3; ++f) B0[f] = BT[(k0 * 3 + f) * 64 + lane];
    }
    uint4 F[6];
    loadA(F, kl[0] & 1023);

    for (int ki = 0; ki + 1 < nk; ++ki) {
        const int gn = kl[ki + 1] & 1023, kn = kl[ki + 1] >> 10;
        uint4 FN[6];
        loadA(FN, gn);
        uint4 BN[3];
#pragma unroll
        for (int f = 0; f < 3; ++f) BN[f] = BT[(kn * 3 + f) * 64 + lane];

#pragma unroll
        for (int ss = 0; ss < 3; ++ss)
#pragma unroll
            for (int r = 0; r < 4; ++r)
                acc[r] = __builtin_amdgcn_mfma_f32_32x32x16_bf16(
                    __builtin_bit_cast(bf16x8, F[r + ss]),
                    __builtin_bit_cast(bf16x8, B0[ss]), acc[r], 0, 0, 0);

#pragma unroll
        for (int f = 0; f < 6; ++f) F[f] = FN[f];
#pragma unroll
        for (int f = 0; f < 3; ++f) B0[f] = BN[f];
    }
#pragma unroll
    for (int ss = 0; ss < 3; ++ss)
#pragma unroll
        for (int r = 0; r < 4; ++r)
            acc[r] = __builtin_amdgcn_mfma_f32_32x32x16_bf16(
                __builtin_bit_cast(bf16x8, F[r + ss]),
                __builtin_bit_cast(bf16x8, B0[ss]), acc[r], 0, 0, 0);

    plane_epilogue(E[wv], acc, bias, outp, b, h1, w1i, rbase, m, hl, lane, wv);
}

// ---------------------------------------------------------------------------
// Layer 2, BOTH branches (merged path): taps over y2a then y2b; epilogue-a
// stashed in registers; single out store (no RMW). LDS: both B-tables;
// E overlays dead BTS[0] behind a barrier after taps-a.
__global__ __launch_bounds__(256, 2) void conv2ab_k(
    const void* __restrict__ y2a, const void* __restrict__ y2b,
    const u32* __restrict__ fta, const u32* __restrict__ ftb,
    const float* __restrict__ bias, float* __restrict__ out)
{
    __shared__ uint4 BTS[2][1728];        // branch tables; E overlays BTS[0]

    const int tid = threadIdx.x;
    {
        const uint4* ga = (const uint4*)fta;
        const uint4* gb = (const uint4*)ftb;
#pragma unroll
        for (int j = 0; j < 7; ++j) {
            const int idx = j * 256 + tid;
            if (idx < 1728) { BTS[0][idx] = ga[idx]; BTS[1][idx] = gb[idx]; }
        }
    }
    __syncthreads();

    const int wgid = blockIdx.x + S * blockIdx.y + 900 * blockIdx.z;
    const int id2  = (wgid & 7) * 450 + (wgid >> 3);
    const int half = id2 & 1;
    int sp = id2 >> 1;
    const int w1i = sp % S; sp /= S;
    const int h1  = sp % S;
    const int b   = sp / S;

    const int lane = tid & 63, wv = tid >> 6;
    const int m = lane & 31, hl = lane >> 5;
    const int rbase = half * 15 + wv * 4;

    int rofs[6];
#pragma unroll
    for (int f = 0; f < 6; ++f) {
        int rr = rbase + f; if (rr > 31) rr = 31;
        rofs[f] = rr * 1024;
    }

    int kl[9], nk = 0;
#pragma unroll
    for (int k12 = 0; k12 < 9; ++k12) {
        const int g1 = h1 + k12 / 3 - 1, g2 = w1i + k12 % 3 - 1;
        if (g1 >= 0 && g1 < S && g2 >= 0 && g2 < S)
            kl[nk++] = (g1 * S + g2) | (k12 << 10);
    }

    f32x16 acc[4];

    auto run_taps = [&](const void* inp, const uint4* BTb) {
#pragma unroll
        for (int r = 0; r < 4; ++r)
#pragma unroll
            for (int e = 0; e < 16; ++e) acc[r][e] = 0.f;
        auto loadA = [&](uint4* Fd, int g) {
            const char* P = (const char*)inp + ((size_t)b * 900 + g) * PLANE
                            + m * 32 + hl * 16;
#pragma unroll
            for (int f = 0; f < 6; ++f)
                Fd[f] = *(const uint4*)(P + rofs[f]);
        };
        uint4 B0[3];
        {
            const int k0 = kl[0] >> 10;
#pragma unroll
            for (int f = 0; f < 3; ++f) B0[f] = BTb[(k0 * 3 + f) * 64 + lane];
        }
        uint4 F[6];
        loadA(F, kl[0] & 1023);
        for (int ki = 0; ki + 1 < nk; ++ki) {
            const int gn = kl[ki + 1] & 1023, kn = kl[ki + 1] >> 10;
            uint4 FN[6];
            loadA(FN, gn);
            uint4 BN[3];
#pragma unroll
            for (int f = 0; f < 3; ++f) BN[f] = BTb[(kn * 3 + f) * 64 + lane];
#pragma unroll
            for (int ss = 0; ss < 3; ++ss)
#pragma unroll
                for (int r = 0; r < 4; ++r)
                    acc[r] = __builtin_amdgcn_mfma_f32_32x32x16_bf16(
                        __builtin_bit_cast(bf16x8, F[r + ss]),
                        __builtin_bit_cast(bf16x8, B0[ss]), acc[r], 0, 0, 0);
#pragma unroll
            for (int f = 0; f < 6; ++f) F[f] = FN[f];
#pragma unroll
            for (int f = 0; f < 3; ++f) B0[f] = BN[f];
        }
#pragma unroll
        for (int ss = 0; ss < 3; ++ss)
#pragma unroll
            for (int r = 0; r < 4; ++r)
                acc[r] = __builtin_amdgcn_mfma_f32_32x32x16_bf16(
                    __builtin_bit_cast(bf16x8, F[r + ss]),
                    __builtin_bit_cast(bf16x8, B0[ss]), acc[r], 0, 0, 0);
    };

    // ---- branch 0 taps ----
    run_taps(y2a, BTS[0]);
    __syncthreads();                      // all waves done with BTS[0]
    float* Ew = (float*)&BTS[0][0] + wv * 1056;   // E overlays dead BTS[0]

    float va[4] = {0.f, 0.f, 0.f, 0.f};
    for (int r = 0; r < 4; ++r) {
        if (wv == 3 && r == 3) continue;
#pragma unroll
        for (int gq = 0; gq < 4; ++gq)
#pragma unroll
            for (int r4 = 0; r4 < 4; ++r4)
                Ew[m * 33 + 4 * hl + 8 * gq + r4] = acc[r][gq * 4 + r4];
        if (lane < 30) {
            const int t = lane;
            va[r] = fmaxf(Ew[t] + Ew[330 + t + 1] + Ew[660 + t + 2] + bias[0], 0.f);
        }
    }

    // ---- branch 1 taps (BTS[1] untouched by E overlay) ----
    run_taps(y2b, BTS[1]);
    for (int r = 0; r < 4; ++r) {
        if (wv == 3 && r == 3) continue;
#pragma unroll
        for (int gq = 0; gq < 4; ++gq)
#pragma unroll
            for (int r4 = 0; r4 < 4; ++r4)
                Ew[m * 33 + 4 * hl + 8 * gq + r4] = acc[r][gq * 4 + r4];
        const int h2 = rbase + r;
        if (lane < 30) {
            const int t = lane;
            float v = fmaxf(Ew[t] + Ew[330 + t + 1] + Ew[660 + t + 2] + bias[0], 0.f);
            out[(size_t)b * S4 + (size_t)(h1 * S + w1i) * 900 + h2 * 30 + t]
                = va[r] + v;
        }
    }
}

// ---------------------------------------------------------------------------
extern "C" void kernel_launch(void* const* d_in, const int* in_sizes, int n_in,
                              void* d_out, int out_size, void* d_ws, size_t ws_size,
                              hipStream_t stream)
{
    const float* x   = (const float*)d_in[0];
    const float* w1p = (const float*)d_in[1];
    const float* b1p = (const float*)d_in[2];
    const float* w2p = (const float*)d_in[3];
    const float* b2p = (const float*)d_in[4];
    const float* w3p = (const float*)d_in[5];
    const float* b3p = (const float*)d_in[6];
    float* out = (float*)d_out;

    u32* ft = (u32*)d_ws;
    const uint4* ftL0 = (const uint4*)d_ws + 6 * 27 * 64;
    u16* y1a = (u16*)((char*)d_ws + 172032);
    u16* y1b = (u16*)((char*)y1a + YBYTES);
    u16* y2a = (u16*)((char*)y1b + YBYTES);

    const u32* f2b0 = ft + (size_t)2 * 27 * 64 * 4;
    const u32* f2b1 = ft + (size_t)3 * 27 * 64 * 4;
    const u32* f3b0 = ft + (size_t)4 * 27 * 64 * 4;
    const u32* f3b1 = ft + (size_t)5 * 27 * 64 * 4;

    dim3 grid(S, S, 4), grid8(S, S, 8), blk(256);

    if (ws_size >= 172032 + 4 * YBYTES) {
        // Merged path: 5 dispatches (1 prep + 4 conv).
        u16* y2b = (u16*)((char*)y2a + YBYTES);
        prep_k<<<1842, blk, 0, stream>>>(ft, w1p, w2p, w3p, y1a, y1b, y2a, y2b);
        conv0ab_k<<<grid, blk, 0, stream>>>(x, ftL0, b1p, (void*)y1a, (void*)y1b);
        conv1ab_k<<<grid8, blk, 0, stream>>>(y1a, y1b, f2b0, f2b1, b2p,
                                             (void*)y2a, (void*)y2b);
        conv2ab_k<<<grid, blk, 0, stream>>>(y2a, y2b, f3b0, f3b1, b3p, out);
    } else if (ws_size >= 172032 + 3 * YBYTES) {
        // R23 merged path (5 conv dispatches), alias y2b = y1a (safe:
        // separate dispatches order L1a before L1b).
        u16* y2b = y1a;
        prep_k<<<1842, blk, 0, stream>>>(ft, w1p, w2p, w3p, y1a, y1b, y2a, y2a);
        conv0ab_k<<<grid, blk, 0, stream>>>(x, ftL0, b1p, (void*)y1a, (void*)y1b);
        conv_k<1, false><<<grid, blk, 0, stream>>>(y1a, f2b0, b2p, (void*)y2a);
        conv_k<1, false><<<grid, blk, 0, stream>>>(y1b, f2b1, b2p, (void*)y2b);
        conv2ab_k<<<grid, blk, 0, stream>>>(y2a, y2b, f3b0, f3b1, b3p, out);
    } else {
        // Fallback: exact R22 path (2 buffers: y1a, y1b-as-y2).
        u16* y1 = y1a;
        u16* y2 = y1b;
        prep_k<<<1842, blk, 0, stream>>>(ft, w1p, w2p, w3p, y1, y2, y2, y2);
        for (int br = 0; br < 2; ++br) {
            const u32* f2 = (br == 0) ? f2b0 : f2b1;
            const u32* f3 = (br == 0) ? f3b0 : f3b1;
            conv0_k<<<grid, blk, 0, stream>>>(x, ftL0 + br * 192, b1p, (void*)y1);
            conv_k<1, false><<<grid, blk, 0, stream>>>(y1, f2, b2p, (void*)y2);
            if (br == 0)
                conv_k<2, false><<<grid, blk, 0, stream>>>(y2, f3, b3p, (void*)out);
            else
                conv_k<2, true><<<grid, blk, 0, stream>>>(y2, f3, b3p, (void*)out);
        }
    }
}